// Round 8
// baseline (19108.994 us; speedup 1.0000x reference)
//
#include <hip/hip_runtime.h>
#include <math.h>
#include <float.h>
#include <mutex>

// Problem constants (match reference)
#define N_PTS  32768
#define NS     2048      // N_PTS/16 downsample
#define CD     256
#define KC     5
#define TPB    512       // kmeans kernel
#define TPB_F  512       // FPS kernel threads/block
#define NB_F   8         // FPS blocks per branch: 4096 pts/block, 8 pts/thread (registers)
#define MAX_IT 100
#define TOLV   1e-3f
#define DYN_K  131072    // kmeans: pos_s(24576) + stag(65792 @24576..90368) + mdbuf(@98304)

struct Sm {
  int   sel[NS];        // FPS-selected indices into the 32768 points
  int   idx[NS];        // cluster assignment of sampled points
  float cm[KC][CD];     // feature-space centroids
  float cc2h[KC];       // 0.5*|c|^2
  float c3[KC][3];      // position-space centroids
  float cnt[KC];        // cluster counts
  float wc[8][KC];      // per-wave count partials
  float redf[8];
  int   redi[8];
  int   far5[KC];
};

// ---------- block reductions (512 threads = 8 waves) ----------
__device__ __forceinline__ void block_argmax(float v, int i, Sm& sm, float& bv, int& bi) {
  #pragma unroll
  for (int off = 32; off; off >>= 1) {
    float v2 = __shfl_xor(v, off);
    int   i2 = __shfl_xor(i, off);
    if (v2 > v || (v2 == v && i2 < i)) { v = v2; i = i2; }
  }
  __syncthreads();
  if ((threadIdx.x & 63) == 0) { sm.redf[threadIdx.x >> 6] = v; sm.redi[threadIdx.x >> 6] = i; }
  __syncthreads();
  bv = sm.redf[0]; bi = sm.redi[0];
  #pragma unroll
  for (int g = 1; g < 8; g++) {
    float v2 = sm.redf[g]; int i2 = sm.redi[g];
    if (v2 > bv || (v2 == bv && i2 < bi)) { bv = v2; bi = i2; }
  }
}

__device__ __forceinline__ float block_sum(float v, Sm& sm) {
  #pragma unroll
  for (int off = 32; off; off >>= 1) v += __shfl_xor(v, off);
  __syncthreads();
  if ((threadIdx.x & 63) == 0) sm.redf[threadIdx.x >> 6] = v;
  __syncthreads();
  float s = 0.f;
  #pragma unroll
  for (int g = 0; g < 8; g++) s += sm.redf[g];
  return s;  // identical in all threads
}

__device__ __forceinline__ void reduce_counts(Sm& sm, float cn[KC]) {
  const int w = threadIdx.x >> 6, l = threadIdx.x & 63;
  #pragma unroll
  for (int k = 0; k < KC; k++) {
    float s = cn[k];
    #pragma unroll
    for (int off = 32; off; off >>= 1) s += __shfl_xor(s, off);
    cn[k] = s;
  }
  __syncthreads();
  if (l == 0) {
    #pragma unroll
    for (int k = 0; k < KC; k++) sm.wc[w][k] = cn[k];
  }
  __syncthreads();
  if (threadIdx.x == 0) {
    #pragma unroll
    for (int k = 0; k < KC; k++) {
      float s = 0.f;
      #pragma unroll
      for (int g = 0; g < 8; g++) s += sm.wc[g][k];
      sm.cnt[k] = s;
    }
  }
  __syncthreads();
}

__device__ void top5(Sm& sm, float* mdbuf) {
  for (int r5 = 0; r5 < KC; r5++) {
    float lv = -1.f; int li = 0x7fffffff;
    #pragma unroll
    for (int r = 0; r < 4; r++) {
      const int i = 4 * threadIdx.x + r;
      const float v = mdbuf[i];
      if (v > lv) { lv = v; li = i; }
    }
    float bv; int bi;
    block_argmax(lv, li, sm, bv, bi);
    if (threadIdx.x == 0) { sm.far5[r5] = bi; mdbuf[bi] = -2.f; }
    __syncthreads();
  }
}

// ---------- kmeans phases on features ----------
// iteration-0 assignment: fea[:, :3] vs 3-d centroids c3
__device__ void assign3(Sm& sm, const float* feaT) {
  const int tid = threadIdx.x;
  const float4 q0 = *(const float4*)&feaT[0 * NS + 4 * tid];
  const float4 q1 = *(const float4*)&feaT[1 * NS + 4 * tid];
  const float4 q2 = *(const float4*)&feaT[2 * NS + 4 * tid];
  const float x0[4] = {q0.x, q0.y, q0.z, q0.w};
  const float x1[4] = {q1.x, q1.y, q1.z, q1.w};
  const float x2[4] = {q2.x, q2.y, q2.z, q2.w};
  float cn[KC] = {0.f, 0.f, 0.f, 0.f, 0.f};
  #pragma unroll
  for (int r = 0; r < 4; r++) {
    float best = FLT_MAX; int bk = 0;
    #pragma unroll
    for (int k = 0; k < KC; k++) {
      const float d0 = x0[r] - sm.c3[k][0];
      const float d1 = x1[r] - sm.c3[k][1];
      const float d2 = x2[r] - sm.c3[k][2];
      const float s = d0 * d0 + d1 * d1 + d2 * d2;
      if (s < best) { best = s; bk = k; }
    }
    sm.idx[4 * tid + r] = bk;
    #pragma unroll
    for (int k = 0; k < KC; k++) cn[k] += (bk == k) ? 1.f : 0.f;
  }
  reduce_counts(sm, cn);
}

// full 256-dim assignment via dot trick: argmin|x-c|^2 == argmax(x.c - 0.5|c|^2)
__device__ void assign_full(Sm& sm, const float* feaT) {
  const int tid = threadIdx.x;
  float dot[KC][4];
  #pragma unroll
  for (int k = 0; k < KC; k++) { dot[k][0]=0.f; dot[k][1]=0.f; dot[k][2]=0.f; dot[k][3]=0.f; }
  #pragma unroll 4
  for (int j = 0; j < CD; j++) {
    const float4 v = *(const float4*)&feaT[(size_t)j * NS + 4 * tid];
    #pragma unroll
    for (int k = 0; k < KC; k++) {
      const float c = sm.cm[k][j];
      dot[k][0] += v.x * c; dot[k][1] += v.y * c;
      dot[k][2] += v.z * c; dot[k][3] += v.w * c;
    }
  }
  float cn[KC] = {0.f, 0.f, 0.f, 0.f, 0.f};
  #pragma unroll
  for (int r = 0; r < 4; r++) {
    float best = dot[0][r] - sm.cc2h[0]; int bk = 0;
    #pragma unroll
    for (int k = 1; k < KC; k++) {
      const float s = dot[k][r] - sm.cc2h[k];
      if (s > best) { best = s; bk = k; }
    }
    sm.idx[4 * tid + r] = bk;
    #pragma unroll
    for (int k = 0; k < KC; k++) cn[k] += (bk == k) ? 1.f : 0.f;
  }
  reduce_counts(sm, cn);
}

// computeCentroids on features: sums/counts -> cm, sse over dims 0..2, empty fixup, cc2h
__device__ float centroids_fea(Sm& sm, float* wbuf, float* mdbuf,
                               const float* fea_all, const float* feaT) {
  const int tid = threadIdx.x, w = tid >> 6, l = tid & 63;
  // per-wave partial sums (wave w owns points [w*256, w*256+256))
  float4 acc[KC];
  #pragma unroll
  for (int k = 0; k < KC; k++) acc[k] = make_float4(0.f, 0.f, 0.f, 0.f);
  #pragma unroll 8
  for (int ii = 0; ii < 256; ii++) {
    const int i = (w << 8) + ii;
    const int k = __builtin_amdgcn_readfirstlane(sm.idx[i]);
    const float4 v = *(const float4*)&fea_all[(size_t)sm.sel[i] * CD + 4 * l];
    switch (k) {
      case 0: acc[0].x += v.x; acc[0].y += v.y; acc[0].z += v.z; acc[0].w += v.w; break;
      case 1: acc[1].x += v.x; acc[1].y += v.y; acc[1].z += v.z; acc[1].w += v.w; break;
      case 2: acc[2].x += v.x; acc[2].y += v.y; acc[2].z += v.z; acc[2].w += v.w; break;
      case 3: acc[3].x += v.x; acc[3].y += v.y; acc[3].z += v.z; acc[3].w += v.w; break;
      default: acc[4].x += v.x; acc[4].y += v.y; acc[4].z += v.z; acc[4].w += v.w; break;
    }
  }
  #pragma unroll
  for (int k = 0; k < KC; k++) *(float4*)&wbuf[(w * KC + k) * CD + 4 * l] = acc[k];
  __syncthreads();
  // reduce 8 waves + divide
  for (int e = tid; e < KC * CD; e += TPB) {
    float s = 0.f;
    #pragma unroll
    for (int g = 0; g < 8; g++) s += wbuf[g * KC * CD + e];
    (&sm.cm[0][0])[e] = s / fmaxf(sm.cnt[e >> 8], 1.f);
  }
  __syncthreads();
  // sse over dims 0..2 (pre-fixup centroids; only non-empty clusters referenced)
  const float4 q0 = *(const float4*)&feaT[0 * NS + 4 * tid];
  const float4 q1 = *(const float4*)&feaT[1 * NS + 4 * tid];
  const float4 q2 = *(const float4*)&feaT[2 * NS + 4 * tid];
  const float x0[4] = {q0.x, q0.y, q0.z, q0.w};
  const float x1[4] = {q1.x, q1.y, q1.z, q1.w};
  const float x2[4] = {q2.x, q2.y, q2.z, q2.w};
  float psum = 0.f;
  #pragma unroll
  for (int r = 0; r < 4; r++) {
    const int k = sm.idx[4 * tid + r];
    const float d0 = x0[r] - sm.cm[k][0];
    const float d1 = x1[r] - sm.cm[k][1];
    const float d2 = x2[r] - sm.cm[k][2];
    psum += d0 * d0 + d1 * d1 + d2 * d2;
  }
  const float sse = sqrtf(block_sum(psum, sm));
  // empty-cluster fixup
  int nmask = 0;
  #pragma unroll
  for (int k = 0; k < KC; k++) nmask |= (sm.cnt[k] == 0.f) ? (1 << k) : 0;
  if (nmask) {
    float4 dd[KC];
    #pragma unroll
    for (int k = 0; k < KC; k++) dd[k] = make_float4(0.f, 0.f, 0.f, 0.f);
    #pragma unroll 4
    for (int j = 0; j < CD; j++) {
      const float4 v = *(const float4*)&feaT[(size_t)j * NS + 4 * tid];
      #pragma unroll
      for (int k = 0; k < KC; k++) {
        const float c = sm.cm[k][j];
        const float t0 = v.x - c, t1 = v.y - c, t2 = v.z - c, t3 = v.w - c;
        dd[k].x += t0 * t0; dd[k].y += t1 * t1; dd[k].z += t2 * t2; dd[k].w += t3 * t3;
      }
    }
    #pragma unroll
    for (int r = 0; r < 4; r++) {
      float s = 0.f;
      #pragma unroll
      for (int k = 0; k < KC; k++) {
        if (sm.cnt[k] > 0.f) {
          const float d2v = (r == 0) ? dd[k].x : (r == 1) ? dd[k].y : (r == 2) ? dd[k].z : dd[k].w;
          s += sqrtf(fmaxf(d2v, 0.f) + 1e-12f);
        }
      }
      mdbuf[4 * tid + r] = s;
    }
    __syncthreads();
    top5(sm, mdbuf);
    int cum = 0;
    for (int k = 0; k < KC; k++) {   // uniform across threads
      if (sm.cnt[k] == 0.f) {
        const int rk = (cum < KC) ? cum : (KC - 1);
        const int src = sm.far5[rk];
        const size_t row = (size_t)sm.sel[src] * CD;
        for (int d = tid; d < CD; d += TPB) sm.cm[k][d] = fea_all[row + d];
        cum++;
      }
    }
    __syncthreads();
  }
  // cc2h (after fixup, for next assignment)
  if (tid < KC * 64) {
    const float4 c = *(const float4*)&sm.cm[w][4 * l];
    float s = c.x * c.x + c.y * c.y + c.z * c.z + c.w * c.w;
    #pragma unroll
    for (int off = 32; off; off >>= 1) s += __shfl_xor(s, off);
    if (l == 0) sm.cc2h[w] = 0.5f * s;
  }
  __syncthreads();
  return sse;
}

// ---------- FPS kernel: 8 blocks/branch x 512 threads, single-barrier low-latency sync ----------
// Round-7 measured 2.66 us/iter; protocol overhead (2 barriers + winLDS round trip +
// serial tid0 reduce + dependent pos[] load) was ~half. This version:
//  - wave-winner lane writes (v,idx,x,y,z) to LDS directly from registers (unique winner:
//    per-lane indices disjoint; tie-break keeps lowest index)
//  - ONE barrier; wave-0 lanes 0..7 shuffle-reduce the 8 wave tuples; lane 0 publishes
//    float4{x,y,z} side-slot THEN release-atomic u64 (bit63|fbits<<32|(~idx) -> u64 max
//    == (max value, min index), matching jnp.argmax first-occurrence)
//  - ALL waves poll the 8 slots independently (lanes 0..7), load the float4 at
//    poll-success (release/acquire message passing), reduce carrying xyz, broadcast.
//    No second barrier (safe: a wave passes the poll only after its own block's publish,
//    which is after wave-0's LDS reads -> next iteration's LDS writes can't race), and
//    no dependent pos[] load on the critical path.
__global__ __launch_bounds__(TPB_F) void fps_kernel(const float* __restrict__ pfirst,
                                                    const float* __restrict__ psec,
                                                    int* __restrict__ sel_base,
                                                    unsigned long long* __restrict__ cand,
                                                    float4* __restrict__ cpos) {
  const int br = blockIdx.x >> 3, sub = blockIdx.x & 7;
  const float* pos = ((br < 2) ? pfirst : psec) + (size_t)(br & 1) * N_PTS * 3;
  int* selg = sel_base + (size_t)br * NS * CD;          // slab-start overlay
  unsigned long long* mycand = cand + (size_t)br * NS * NB_F;
  float4* mycpos = cpos + (size_t)br * NS * NB_F;
  __shared__ float redf[8], redx[8], redy[8], redz[8];
  __shared__ int   redi[8];
  const int tid = threadIdx.x, w = tid >> 6, l = tid & 63;
  const int base = sub * 4096;

  float px[8], py[8], pz[8], dd[8];          // 32 registers, static indices only
  #pragma unroll
  for (int k = 0; k < 8; k++) {
    const int p = base + tid + k * TPB_F;
    px[k] = pos[3 * p]; py[k] = pos[3 * p + 1]; pz[k] = pos[3 * p + 2];
    dd[k] = 1e10f;
  }
  if (sub == 0 && tid == 0) selg[0] = 0;
  float lx = pos[0], ly = pos[1], lz = pos[2];

  for (int t = 1; t < NS; t++) {
    // register-only update + local argmax, tracking candidate position in registers
    float bv = -1.f, bx = 0.f, by = 0.f, bz = 0.f; int bi = 0x7fffffff;
    #pragma unroll
    for (int k = 0; k < 8; k++) {
      const float dx = px[k] - lx, dy = py[k] - ly, dz = pz[k] - lz;
      dd[k] = fminf(dd[k], dx * dx + dy * dy + dz * dz);
      if (dd[k] > bv) { bv = dd[k]; bi = base + tid + k * TPB_F; bx = px[k]; by = py[k]; bz = pz[k]; }
    }
    const int myi = bi;
    // wave-level (value desc, index asc) argmax
    #pragma unroll
    for (int off = 32; off; off >>= 1) {
      const float v2 = __shfl_xor(bv, off);
      const int   i2 = __shfl_xor(bi, off);
      if (v2 > bv || (v2 == bv && i2 < bi)) { bv = v2; bi = i2; }
    }
    // unique wave-winner lane publishes its tuple to LDS (from registers)
    if (myi == bi) { redf[w] = bv; redi[w] = bi; redx[w] = bx; redy[w] = by; redz[w] = bz; }
    __syncthreads();
    // wave 0, lanes 0..7: block-level shuffle reduce + publish
    if (w == 0) {
      float cv = -1.f, cx = 0.f, cy = 0.f, cz = 0.f; int ci = 0x7fffffff;
      if (l < 8) { cv = redf[l]; ci = redi[l]; cx = redx[l]; cy = redy[l]; cz = redz[l]; }
      #pragma unroll
      for (int off = 4; off; off >>= 1) {
        const float v2 = __shfl_xor(cv, off);
        const int   i2 = __shfl_xor(ci, off);
        const float x2 = __shfl_xor(cx, off);
        const float y2 = __shfl_xor(cy, off);
        const float z2 = __shfl_xor(cz, off);
        if (v2 > cv || (v2 == cv && i2 < ci)) { cv = v2; ci = i2; cx = x2; cy = y2; cz = z2; }
      }
      if (l == 0) {
        mycpos[(size_t)t * NB_F + sub] = make_float4(cx, cy, cz, 0.f);  // before release store
        const unsigned long long pk = (1ULL << 63)
            | ((unsigned long long)__float_as_uint(cv) << 32)
            | (unsigned long long)(0xFFFFFFFFu - (unsigned)ci);
        __hip_atomic_store(&mycand[(size_t)t * NB_F + sub], pk,
                           __ATOMIC_RELEASE, __HIP_MEMORY_SCOPE_AGENT);
      }
    }
    // ALL waves: lanes 0..7 poll slots + load positions; reduce carrying xyz; broadcast
    unsigned long long pk = 0ULL; float fx = 0.f, fy = 0.f, fz = 0.f;
    if (l < NB_F) {
      pk = __hip_atomic_load(&mycand[(size_t)t * NB_F + l],
                             __ATOMIC_ACQUIRE, __HIP_MEMORY_SCOPE_AGENT);
      while (pk == 0ULL) {
        __builtin_amdgcn_s_sleep(1);
        pk = __hip_atomic_load(&mycand[(size_t)t * NB_F + l],
                               __ATOMIC_ACQUIRE, __HIP_MEMORY_SCOPE_AGENT);
      }
      const float4 c4 = mycpos[(size_t)t * NB_F + l];   // valid: release/acquire ordering
      fx = c4.x; fy = c4.y; fz = c4.z;
    }
    #pragma unroll
    for (int off = 4; off; off >>= 1) {
      const unsigned long long o = __shfl_xor(pk, off);
      const float x2 = __shfl_xor(fx, off);
      const float y2 = __shfl_xor(fy, off);
      const float z2 = __shfl_xor(fz, off);
      if (o > pk) { pk = o; fx = x2; fy = y2; fz = z2; }   // pk has bit63 -> garbage lanes lose
    }
    lx = __shfl(fx, 0); ly = __shfl(fy, 0); lz = __shfl(fz, 0);
    if (sub == 0 && tid == 0)
      selg[t] = (int)(0xFFFFFFFFu - (unsigned)(pk & 0xFFFFFFFFull));  // lane0 pk = reduced max
  }
}

// ---------- per-branch kmeans kernel (512 threads; round-7-verified code) ----------
__global__ __launch_bounds__(TPB) void branch_kernel(const float* __restrict__ logits,
                                                     const float* __restrict__ logits1,
                                                     const float* __restrict__ pfirst,
                                                     const float* __restrict__ psec,
                                                     float* __restrict__ feaT_base,
                                                     float* __restrict__ accum) {
  const int b = blockIdx.x;                  // 0,1 -> logits/p0first; 2,3 -> logits1/p0sec
  const float* fea_all = ((b < 2) ? logits : logits1) + (size_t)(b & 1) * N_PTS * CD;
  const float* pos     = ((b < 2) ? pfirst : psec) + (size_t)(b & 1) * N_PTS * 3;
  float* feaT = feaT_base + (size_t)b * NS * CD;   // [CD][NS] transposed sampled features
  const int* selg = (const int*)feaT;              // overlay: read fully before feaT writes

  __shared__ Sm sm;
  extern __shared__ char dynraw[];
  const int tid = threadIdx.x, w = tid >> 6, l = tid & 63;

  // load FPS selection (must complete before any feaT write - barrier below)
  for (int i = tid; i < NS; i += TPB) sm.sel[i] = selg[i];
  __syncthreads();

  // ================= gather sampled pos into LDS =================
  float* pos_s = (float*)dynraw;             // [NS*3] 0..24576
  float* stag  = (float*)(dynraw + 24576);   // [64][257] = 65792 B -> 24576..90368
  float* wbuf  = (float*)(dynraw + 24576);   // 40960 B, reused after transpose
  float* mdbuf = (float*)(dynraw + 98304);   // [NS] 8192 B -> 98304..106496 (clear of stag)
  for (int i = tid; i < NS; i += TPB) {
    const int s = sm.sel[i];
    pos_s[3 * i] = pos[3 * s]; pos_s[3 * i + 1] = pos[3 * s + 1]; pos_s[3 * i + 2] = pos[3 * s + 2];
  }

  // ================= gather + transpose sampled features -> feaT =================
  for (int tile = 0; tile < NS; tile += 64) {
    __syncthreads();
    for (int rr = w; rr < 64; rr += 8) {
      const int srow = sm.sel[tile + rr];
      const float4 v = *(const float4*)&fea_all[(size_t)srow * CD + 4 * l];
      float* dst = &stag[rr * 257 + 4 * l];
      dst[0] = v.x; dst[1] = v.y; dst[2] = v.z; dst[3] = v.w;
    }
    __syncthreads();
    for (int dd = 0; dd < 32; dd++) {
      const int dim = w * 32 + dd;
      feaT[(size_t)dim * NS + tile + l] = stag[l * 257 + dim];
    }
  }
  __syncthreads();

  // ================= initial centroids (greedy, on positions) =================
  if (tid == 0) { sm.c3[0][0] = pos_s[0]; sm.c3[0][1] = pos_s[1]; sm.c3[0][2] = pos_s[2]; }
  __syncthreads();
  for (int k = 1; k < KC; k++) {
    float lv = -1.f; int li = 0x7fffffff;
    #pragma unroll
    for (int r = 0; r < 4; r++) {
      const int i = 4 * tid + r;
      const float x = pos_s[3 * i], y = pos_s[3 * i + 1], z = pos_s[3 * i + 2];
      float a = 0.f;
      for (int j = 0; j < k; j++) {
        const float dx = x - sm.c3[j][0], dy = y - sm.c3[j][1], dz = z - sm.c3[j][2];
        a += dx * dx + dy * dy + dz * dz;
      }
      if (a > lv) { lv = a; li = i; }
    }
    float bv; int bi;
    block_argmax(lv, li, sm, bv, bi);
    if (tid == 0) { sm.c3[k][0] = pos_s[3 * bi]; sm.c3[k][1] = pos_s[3 * bi + 1]; sm.c3[k][2] = pos_s[3 * bi + 2]; }
    __syncthreads();
  }

  // ================= one kmeans step on positions =================
  {
    float a3[KC][3]; float cn[KC];
    #pragma unroll
    for (int k = 0; k < KC; k++) { a3[k][0] = 0.f; a3[k][1] = 0.f; a3[k][2] = 0.f; cn[k] = 0.f; }
    #pragma unroll
    for (int r = 0; r < 4; r++) {
      const int i = 4 * tid + r;
      const float x = pos_s[3 * i], y = pos_s[3 * i + 1], z = pos_s[3 * i + 2];
      float best = FLT_MAX; int bk = 0;
      #pragma unroll
      for (int k = 0; k < KC; k++) {
        const float dx = x - sm.c3[k][0], dy = y - sm.c3[k][1], dz = z - sm.c3[k][2];
        const float s = dx * dx + dy * dy + dz * dz;
        if (s < best) { best = s; bk = k; }
      }
      sm.idx[i] = bk;
      #pragma unroll
      for (int k = 0; k < KC; k++) {
        const float m = (bk == k) ? 1.f : 0.f;
        a3[k][0] += m * x; a3[k][1] += m * y; a3[k][2] += m * z; cn[k] += m;
      }
    }
    reduce_counts(sm, cn);
    #pragma unroll
    for (int k = 0; k < KC; k++) {
      #pragma unroll
      for (int c = 0; c < 3; c++) {
        float s = a3[k][c];
        #pragma unroll
        for (int off = 32; off; off >>= 1) s += __shfl_xor(s, off);
        a3[k][c] = s;
      }
    }
    __syncthreads();
    if (l == 0) {
      #pragma unroll
      for (int k = 0; k < KC; k++) {
        wbuf[w * 16 + k * 3 + 0] = a3[k][0];
        wbuf[w * 16 + k * 3 + 1] = a3[k][1];
        wbuf[w * 16 + k * 3 + 2] = a3[k][2];
      }
    }
    __syncthreads();
    if (tid == 0) {
      for (int k = 0; k < KC; k++)
        for (int c = 0; c < 3; c++) {
          float s = 0.f;
          for (int g = 0; g < 8; g++) s += wbuf[g * 16 + k * 3 + c];
          sm.c3[k][c] = s / fmaxf(sm.cnt[k], 1.f);
        }
    }
    __syncthreads();
  }
  float psum = 0.f;
  #pragma unroll
  for (int r = 0; r < 4; r++) {
    const int i = 4 * tid + r; const int k = sm.idx[i];
    const float dx = pos_s[3 * i] - sm.c3[k][0];
    const float dy = pos_s[3 * i + 1] - sm.c3[k][1];
    const float dz = pos_s[3 * i + 2] - sm.c3[k][2];
    psum += dx * dx + dy * dy + dz * dz;
  }
  const float sse_n = sqrtf(block_sum(psum, sm));
  {  // empty-cluster fixup (positions)
    int nmask = 0;
    #pragma unroll
    for (int k = 0; k < KC; k++) nmask |= (sm.cnt[k] == 0.f) ? (1 << k) : 0;
    if (nmask) {
      #pragma unroll
      for (int r = 0; r < 4; r++) {
        const int i = 4 * tid + r;
        const float x = pos_s[3 * i], y = pos_s[3 * i + 1], z = pos_s[3 * i + 2];
        float s = 0.f;
        for (int k = 0; k < KC; k++) {
          if (sm.cnt[k] > 0.f) {
            const float dx = x - sm.c3[k][0], dy = y - sm.c3[k][1], dz = z - sm.c3[k][2];
            s += sqrtf(dx * dx + dy * dy + dz * dz + 1e-12f);
          }
        }
        mdbuf[i] = s;
      }
      __syncthreads();
      top5(sm, mdbuf);
      if (tid == 0) {
        int cum = 0;
        for (int k = 0; k < KC; k++) {
          if (sm.cnt[k] == 0.f) {
            const int rk = (cum < KC) ? cum : (KC - 1);
            const int src = sm.far5[rk];
            sm.c3[k][0] = pos_s[3 * src]; sm.c3[k][1] = pos_s[3 * src + 1]; sm.c3[k][2] = pos_s[3 * src + 2];
            cum++;
          }
        }
      }
      __syncthreads();
    }
  }

  // ================= kmeans on features =================
  assign3(sm, feaT);
  float sse_fin = centroids_fea(sm, wbuf, mdbuf, fea_all, feaT);
  float sse_pre = sse_fin;
  bool done = fabsf(sse_fin) < TOLV;
  for (int it = 1; it < MAX_IT && !done; it++) {
    assign_full(sm, feaT);
    const float s2 = centroids_fea(sm, wbuf, mdbuf, fea_all, feaT);
    sse_fin = s2;
    done = fabsf(s2 - sse_pre) < TOLV;
    sse_pre = s2;
  }
  if (tid == 0) atomicAdd(&accum[1], sse_n + sse_fin);
}

// ---------- global point loss (cosine similarity) ----------
__global__ __launch_bounds__(256) void gp_kernel(const float* __restrict__ A,
                                                 const float* __restrict__ B,
                                                 float* __restrict__ accum) {
  __shared__ float bacc;
  const int tid = threadIdx.x, l = tid & 63, w = tid >> 6;
  if (tid == 0) bacc = 0.f;
  __syncthreads();
  const int gw = blockIdx.x * 4 + w;
  const int NW = gridDim.x * 4;
  float lsum = 0.f;
  for (int p = gw; p < 65536; p += NW) {
    const float4 a = *(const float4*)&A[(size_t)p * CD + 4 * l];
    const float4 b = *(const float4*)&B[(size_t)p * CD + 4 * l];
    float ab = a.x * b.x + a.y * b.y + a.z * b.z + a.w * b.w;
    float aa = a.x * a.x + a.y * a.y + a.z * a.z + a.w * a.w;
    float bb = b.x * b.x + b.y * b.y + b.z * b.z + b.w * b.w;
    #pragma unroll
    for (int off = 32; off; off >>= 1) {
      ab += __shfl_xor(ab, off); aa += __shfl_xor(aa, off); bb += __shfl_xor(bb, off);
    }
    if (l == 0) lsum += ab / fmaxf(sqrtf(aa) * sqrtf(bb), 1e-8f);
  }
  if (l == 0) atomicAdd(&bacc, lsum);
  __syncthreads();
  if (tid == 0) atomicAdd(&accum[0], bacc);
}

__global__ void fin_kernel(const float* __restrict__ accum, float* __restrict__ out) {
  out[0] = -accum[0] / 65536.0f + accum[1];
}

extern "C" void kernel_launch(void* const* d_in, const int* in_sizes, int n_in,
                              void* d_out, int out_size, void* d_ws, size_t ws_size,
                              hipStream_t stream) {
  const float* logits  = (const float*)d_in[0];
  const float* logits1 = (const float*)d_in[1];
  const float* pfirst  = (const float*)d_in[2];
  const float* psec    = (const float*)d_in[3];
  float* out = (float*)d_out;
  float* wsf = (float*)d_ws;
  float* accum = wsf;                                  // [0]=sum of cos, [1]=sum of sse
  unsigned long long* cand = (unsigned long long*)(wsf + 16);      // 4*NS*8 u64 = 512 KB
  float4* cpos = (float4*)(wsf + 16 + 4 * NS * NB_F * 2);          // 4*NS*8 float4 = 1 MB
  float* feaT = wsf + 16 + 4 * NS * NB_F * 2 + 4 * NS * NB_F * 4;  // 8 MB; 16B-aligned

  static std::once_flag once;
  std::call_once(once, []() {
    (void)hipFuncSetAttribute((const void*)branch_kernel,
                              hipFuncAttributeMaxDynamicSharedMemorySize, DYN_K);
    (void)hipGetLastError();
  });

  // zero accum + ALL cand flag slots (fresh slots each launch -> poll is ABA-free;
  // cpos needs no zeroing - guarded by the cand release/acquire handshake)
  (void)hipMemsetAsync(wsf, 0, 64 + (size_t)4 * NS * NB_F * 8, stream);
  gp_kernel<<<1024, 256, 0, stream>>>(logits, logits1, accum);
  fps_kernel<<<4 * NB_F, TPB_F, 0, stream>>>(pfirst, psec, (int*)feaT, cand, cpos);
  branch_kernel<<<4, TPB, DYN_K, stream>>>(logits, logits1, pfirst, psec, feaT, accum);
  fin_kernel<<<1, 1, 0, stream>>>(accum, out);
}

// Round 9
// 10058.920 us; speedup vs baseline: 1.8997x; 1.8997x over previous
//
#include <hip/hip_runtime.h>
#include <math.h>
#include <float.h>
#include <mutex>

// Problem constants (match reference)
#define N_PTS  32768
#define NS     2048      // N_PTS/16 downsample
#define CD     256
#define KC     5
#define TPB    512       // kmeans kernel
#define TPB_F  512       // FPS kernel threads/block
#define NB_F   8         // FPS blocks per branch: 4096 pts/block, 8 pts/thread (registers)
#define MAX_IT 100
#define TOLV   1e-3f
#define DYN_K  131072    // kmeans: pos_s(24576) + stag(65792 @24576..90368) + mdbuf(@98304)

struct Sm {
  int   sel[NS];        // FPS-selected indices into the 32768 points
  int   idx[NS];        // cluster assignment of sampled points
  float cm[KC][CD];     // feature-space centroids
  float cc2h[KC];       // 0.5*|c|^2
  float c3[KC][3];      // position-space centroids
  float cnt[KC];        // cluster counts
  float wc[8][KC];      // per-wave count partials
  float redf[8];
  int   redi[8];
  int   far5[KC];
};

// ---------- block reductions (512 threads = 8 waves) ----------
__device__ __forceinline__ void block_argmax(float v, int i, Sm& sm, float& bv, int& bi) {
  #pragma unroll
  for (int off = 32; off; off >>= 1) {
    float v2 = __shfl_xor(v, off);
    int   i2 = __shfl_xor(i, off);
    if (v2 > v || (v2 == v && i2 < i)) { v = v2; i = i2; }
  }
  __syncthreads();
  if ((threadIdx.x & 63) == 0) { sm.redf[threadIdx.x >> 6] = v; sm.redi[threadIdx.x >> 6] = i; }
  __syncthreads();
  bv = sm.redf[0]; bi = sm.redi[0];
  #pragma unroll
  for (int g = 1; g < 8; g++) {
    float v2 = sm.redf[g]; int i2 = sm.redi[g];
    if (v2 > bv || (v2 == bv && i2 < bi)) { bv = v2; bi = i2; }
  }
}

__device__ __forceinline__ float block_sum(float v, Sm& sm) {
  #pragma unroll
  for (int off = 32; off; off >>= 1) v += __shfl_xor(v, off);
  __syncthreads();
  if ((threadIdx.x & 63) == 0) sm.redf[threadIdx.x >> 6] = v;
  __syncthreads();
  float s = 0.f;
  #pragma unroll
  for (int g = 0; g < 8; g++) s += sm.redf[g];
  return s;  // identical in all threads
}

__device__ __forceinline__ void reduce_counts(Sm& sm, float cn[KC]) {
  const int w = threadIdx.x >> 6, l = threadIdx.x & 63;
  #pragma unroll
  for (int k = 0; k < KC; k++) {
    float s = cn[k];
    #pragma unroll
    for (int off = 32; off; off >>= 1) s += __shfl_xor(s, off);
    cn[k] = s;
  }
  __syncthreads();
  if (l == 0) {
    #pragma unroll
    for (int k = 0; k < KC; k++) sm.wc[w][k] = cn[k];
  }
  __syncthreads();
  if (threadIdx.x == 0) {
    #pragma unroll
    for (int k = 0; k < KC; k++) {
      float s = 0.f;
      #pragma unroll
      for (int g = 0; g < 8; g++) s += sm.wc[g][k];
      sm.cnt[k] = s;
    }
  }
  __syncthreads();
}

__device__ void top5(Sm& sm, float* mdbuf) {
  for (int r5 = 0; r5 < KC; r5++) {
    float lv = -1.f; int li = 0x7fffffff;
    #pragma unroll
    for (int r = 0; r < 4; r++) {
      const int i = 4 * threadIdx.x + r;
      const float v = mdbuf[i];
      if (v > lv) { lv = v; li = i; }
    }
    float bv; int bi;
    block_argmax(lv, li, sm, bv, bi);
    if (threadIdx.x == 0) { sm.far5[r5] = bi; mdbuf[bi] = -2.f; }
    __syncthreads();
  }
}

// ---------- kmeans phases on features ----------
// iteration-0 assignment: fea[:, :3] vs 3-d centroids c3
__device__ void assign3(Sm& sm, const float* feaT) {
  const int tid = threadIdx.x;
  const float4 q0 = *(const float4*)&feaT[0 * NS + 4 * tid];
  const float4 q1 = *(const float4*)&feaT[1 * NS + 4 * tid];
  const float4 q2 = *(const float4*)&feaT[2 * NS + 4 * tid];
  const float x0[4] = {q0.x, q0.y, q0.z, q0.w};
  const float x1[4] = {q1.x, q1.y, q1.z, q1.w};
  const float x2[4] = {q2.x, q2.y, q2.z, q2.w};
  float cn[KC] = {0.f, 0.f, 0.f, 0.f, 0.f};
  #pragma unroll
  for (int r = 0; r < 4; r++) {
    float best = FLT_MAX; int bk = 0;
    #pragma unroll
    for (int k = 0; k < KC; k++) {
      const float d0 = x0[r] - sm.c3[k][0];
      const float d1 = x1[r] - sm.c3[k][1];
      const float d2 = x2[r] - sm.c3[k][2];
      const float s = d0 * d0 + d1 * d1 + d2 * d2;
      if (s < best) { best = s; bk = k; }
    }
    sm.idx[4 * tid + r] = bk;
    #pragma unroll
    for (int k = 0; k < KC; k++) cn[k] += (bk == k) ? 1.f : 0.f;
  }
  reduce_counts(sm, cn);
}

// full 256-dim assignment via dot trick: argmin|x-c|^2 == argmax(x.c - 0.5|c|^2)
__device__ void assign_full(Sm& sm, const float* feaT) {
  const int tid = threadIdx.x;
  float dot[KC][4];
  #pragma unroll
  for (int k = 0; k < KC; k++) { dot[k][0]=0.f; dot[k][1]=0.f; dot[k][2]=0.f; dot[k][3]=0.f; }
  #pragma unroll 4
  for (int j = 0; j < CD; j++) {
    const float4 v = *(const float4*)&feaT[(size_t)j * NS + 4 * tid];
    #pragma unroll
    for (int k = 0; k < KC; k++) {
      const float c = sm.cm[k][j];
      dot[k][0] += v.x * c; dot[k][1] += v.y * c;
      dot[k][2] += v.z * c; dot[k][3] += v.w * c;
    }
  }
  float cn[KC] = {0.f, 0.f, 0.f, 0.f, 0.f};
  #pragma unroll
  for (int r = 0; r < 4; r++) {
    float best = dot[0][r] - sm.cc2h[0]; int bk = 0;
    #pragma unroll
    for (int k = 1; k < KC; k++) {
      const float s = dot[k][r] - sm.cc2h[k];
      if (s > best) { best = s; bk = k; }
    }
    sm.idx[4 * tid + r] = bk;
    #pragma unroll
    for (int k = 0; k < KC; k++) cn[k] += (bk == k) ? 1.f : 0.f;
  }
  reduce_counts(sm, cn);
}

// computeCentroids on features: sums/counts -> cm, sse over dims 0..2, empty fixup, cc2h
__device__ float centroids_fea(Sm& sm, float* wbuf, float* mdbuf,
                               const float* fea_all, const float* feaT) {
  const int tid = threadIdx.x, w = tid >> 6, l = tid & 63;
  // per-wave partial sums (wave w owns points [w*256, w*256+256))
  float4 acc[KC];
  #pragma unroll
  for (int k = 0; k < KC; k++) acc[k] = make_float4(0.f, 0.f, 0.f, 0.f);
  #pragma unroll 8
  for (int ii = 0; ii < 256; ii++) {
    const int i = (w << 8) + ii;
    const int k = __builtin_amdgcn_readfirstlane(sm.idx[i]);
    const float4 v = *(const float4*)&fea_all[(size_t)sm.sel[i] * CD + 4 * l];
    switch (k) {
      case 0: acc[0].x += v.x; acc[0].y += v.y; acc[0].z += v.z; acc[0].w += v.w; break;
      case 1: acc[1].x += v.x; acc[1].y += v.y; acc[1].z += v.z; acc[1].w += v.w; break;
      case 2: acc[2].x += v.x; acc[2].y += v.y; acc[2].z += v.z; acc[2].w += v.w; break;
      case 3: acc[3].x += v.x; acc[3].y += v.y; acc[3].z += v.z; acc[3].w += v.w; break;
      default: acc[4].x += v.x; acc[4].y += v.y; acc[4].z += v.z; acc[4].w += v.w; break;
    }
  }
  #pragma unroll
  for (int k = 0; k < KC; k++) *(float4*)&wbuf[(w * KC + k) * CD + 4 * l] = acc[k];
  __syncthreads();
  // reduce 8 waves + divide
  for (int e = tid; e < KC * CD; e += TPB) {
    float s = 0.f;
    #pragma unroll
    for (int g = 0; g < 8; g++) s += wbuf[g * KC * CD + e];
    (&sm.cm[0][0])[e] = s / fmaxf(sm.cnt[e >> 8], 1.f);
  }
  __syncthreads();
  // sse over dims 0..2 (pre-fixup centroids; only non-empty clusters referenced)
  const float4 q0 = *(const float4*)&feaT[0 * NS + 4 * tid];
  const float4 q1 = *(const float4*)&feaT[1 * NS + 4 * tid];
  const float4 q2 = *(const float4*)&feaT[2 * NS + 4 * tid];
  const float x0[4] = {q0.x, q0.y, q0.z, q0.w};
  const float x1[4] = {q1.x, q1.y, q1.z, q1.w};
  const float x2[4] = {q2.x, q2.y, q2.z, q2.w};
  float psum = 0.f;
  #pragma unroll
  for (int r = 0; r < 4; r++) {
    const int k = sm.idx[4 * tid + r];
    const float d0 = x0[r] - sm.cm[k][0];
    const float d1 = x1[r] - sm.cm[k][1];
    const float d2 = x2[r] - sm.cm[k][2];
    psum += d0 * d0 + d1 * d1 + d2 * d2;
  }
  const float sse = sqrtf(block_sum(psum, sm));
  // empty-cluster fixup
  int nmask = 0;
  #pragma unroll
  for (int k = 0; k < KC; k++) nmask |= (sm.cnt[k] == 0.f) ? (1 << k) : 0;
  if (nmask) {
    float4 dd[KC];
    #pragma unroll
    for (int k = 0; k < KC; k++) dd[k] = make_float4(0.f, 0.f, 0.f, 0.f);
    #pragma unroll 4
    for (int j = 0; j < CD; j++) {
      const float4 v = *(const float4*)&feaT[(size_t)j * NS + 4 * tid];
      #pragma unroll
      for (int k = 0; k < KC; k++) {
        const float c = sm.cm[k][j];
        const float t0 = v.x - c, t1 = v.y - c, t2 = v.z - c, t3 = v.w - c;
        dd[k].x += t0 * t0; dd[k].y += t1 * t1; dd[k].z += t2 * t2; dd[k].w += t3 * t3;
      }
    }
    #pragma unroll
    for (int r = 0; r < 4; r++) {
      float s = 0.f;
      #pragma unroll
      for (int k = 0; k < KC; k++) {
        if (sm.cnt[k] > 0.f) {
          const float d2v = (r == 0) ? dd[k].x : (r == 1) ? dd[k].y : (r == 2) ? dd[k].z : dd[k].w;
          s += sqrtf(fmaxf(d2v, 0.f) + 1e-12f);
        }
      }
      mdbuf[4 * tid + r] = s;
    }
    __syncthreads();
    top5(sm, mdbuf);
    int cum = 0;
    for (int k = 0; k < KC; k++) {   // uniform across threads
      if (sm.cnt[k] == 0.f) {
        const int rk = (cum < KC) ? cum : (KC - 1);
        const int src = sm.far5[rk];
        const size_t row = (size_t)sm.sel[src] * CD;
        for (int d = tid; d < CD; d += TPB) sm.cm[k][d] = fea_all[row + d];
        cum++;
      }
    }
    __syncthreads();
  }
  // cc2h (after fixup, for next assignment)
  if (tid < KC * 64) {
    const float4 c = *(const float4*)&sm.cm[w][4 * l];
    float s = c.x * c.x + c.y * c.y + c.z * c.z + c.w * c.w;
    #pragma unroll
    for (int off = 32; off; off >>= 1) s += __shfl_xor(s, off);
    if (l == 0) sm.cc2h[w] = 0.5f * s;
  }
  __syncthreads();
  return sse;
}

// ---------- FPS kernel: 8 blocks/branch x 512 threads ----------
// Round-7 protocol shape RESTORED (round 8's all-wave polling 8x'd the cross-XCD
// fabric traffic: FETCH 10->23.6 MB, 3x slower). Wave 0 is the ONLY poller; result
// broadcast through LDS + barrier. Traffic-neutral improvements kept from round 8:
//  - winner-lane LDS publish + wave-0 shuffle block-reduce (no serial tid0 chain)
//  - cpos float4 side-channel read ONLY by wave-0's 8 polling lanes; winner xyz
//    broadcast via LDS -> dependent pos[] load off the critical path
//  - XCD grouping: br = blockIdx&3, sub = blockIdx>>2 -> under round-robin
//    blockIdx%%8->XCD mapping, each branch's sync lines live on ~2 XCD L2s, not 8.
// Packing: u64 = bit63 | fbits<<32 | (0xFFFFFFFF-idx) -> u64 max == (max value,
// min index) == jnp.argmax first-occurrence. Fresh per-t slots (memset per launch).
__global__ __launch_bounds__(TPB_F) void fps_kernel(const float* __restrict__ pfirst,
                                                    const float* __restrict__ psec,
                                                    int* __restrict__ sel_base,
                                                    unsigned long long* __restrict__ cand,
                                                    float4* __restrict__ cpos) {
  const int br = blockIdx.x & 3, sub = blockIdx.x >> 2;   // XCD-grouped mapping
  const float* pos = ((br < 2) ? pfirst : psec) + (size_t)(br & 1) * N_PTS * 3;
  int* selg = sel_base + (size_t)br * NS * CD;            // slab-start overlay
  unsigned long long* mycand = cand + (size_t)br * NS * NB_F;
  float4* mycpos = cpos + (size_t)br * NS * NB_F;
  __shared__ float redf[8], redx[8], redy[8], redz[8];
  __shared__ int   redi[8];
  __shared__ float winx, winy, winz;
  const int tid = threadIdx.x, w = tid >> 6, l = tid & 63;
  const int base = sub * 4096;

  float px[8], py[8], pz[8], dd[8];          // 32 registers, static indices only
  #pragma unroll
  for (int k = 0; k < 8; k++) {
    const int p = base + tid + k * TPB_F;
    px[k] = pos[3 * p]; py[k] = pos[3 * p + 1]; pz[k] = pos[3 * p + 2];
    dd[k] = 1e10f;
  }
  if (sub == 0 && tid == 0) selg[0] = 0;
  float lx = pos[0], ly = pos[1], lz = pos[2];

  for (int t = 1; t < NS; t++) {
    // register-only update + local argmax, tracking candidate position in registers
    float bv = -1.f, bx = 0.f, by = 0.f, bz = 0.f; int bi = 0x7fffffff;
    #pragma unroll
    for (int k = 0; k < 8; k++) {
      const float dx = px[k] - lx, dy = py[k] - ly, dz = pz[k] - lz;
      dd[k] = fminf(dd[k], dx * dx + dy * dy + dz * dz);
      if (dd[k] > bv) { bv = dd[k]; bi = base + tid + k * TPB_F; bx = px[k]; by = py[k]; bz = pz[k]; }
    }
    const int myi = bi;
    // wave-level (value desc, index asc) argmax
    #pragma unroll
    for (int off = 32; off; off >>= 1) {
      const float v2 = __shfl_xor(bv, off);
      const int   i2 = __shfl_xor(bi, off);
      if (v2 > bv || (v2 == bv && i2 < bi)) { bv = v2; bi = i2; }
    }
    // unique wave-winner lane publishes its tuple to LDS (indices disjoint per lane)
    if (myi == bi) { redf[w] = bv; redi[w] = bi; redx[w] = bx; redy[w] = by; redz[w] = bz; }
    __syncthreads();
    // wave 0 only: block shuffle-reduce -> publish -> poll -> LDS broadcast
    if (w == 0) {
      float cv = -1.f, cx = 0.f, cy = 0.f, cz = 0.f; int ci = 0x7fffffff;
      if (l < 8) { cv = redf[l]; ci = redi[l]; cx = redx[l]; cy = redy[l]; cz = redz[l]; }
      #pragma unroll
      for (int off = 4; off; off >>= 1) {
        const float v2 = __shfl_xor(cv, off);
        const int   i2 = __shfl_xor(ci, off);
        const float x2 = __shfl_xor(cx, off);
        const float y2 = __shfl_xor(cy, off);
        const float z2 = __shfl_xor(cz, off);
        if (v2 > cv || (v2 == cv && i2 < ci)) { cv = v2; ci = i2; cx = x2; cy = y2; cz = z2; }
      }
      if (l == 0) {
        mycpos[(size_t)t * NB_F + sub] = make_float4(cx, cy, cz, 0.f);  // before release store
        const unsigned long long pk = (1ULL << 63)
            | ((unsigned long long)__float_as_uint(cv) << 32)
            | (unsigned long long)(0xFFFFFFFFu - (unsigned)ci);
        __hip_atomic_store(&mycand[(size_t)t * NB_F + sub], pk,
                           __ATOMIC_RELEASE, __HIP_MEMORY_SCOPE_AGENT);
      }
      // lanes 0..7 poll the 8 slots; float4 read valid via release/acquire ordering
      unsigned long long pk2 = 0ULL; float fx = 0.f, fy = 0.f, fz = 0.f;
      if (l < NB_F) {
        pk2 = __hip_atomic_load(&mycand[(size_t)t * NB_F + l],
                                __ATOMIC_ACQUIRE, __HIP_MEMORY_SCOPE_AGENT);
        while (pk2 == 0ULL) {
          __builtin_amdgcn_s_sleep(1);
          pk2 = __hip_atomic_load(&mycand[(size_t)t * NB_F + l],
                                  __ATOMIC_ACQUIRE, __HIP_MEMORY_SCOPE_AGENT);
        }
        const float4 c4 = mycpos[(size_t)t * NB_F + l];
        fx = c4.x; fy = c4.y; fz = c4.z;
      }
      #pragma unroll
      for (int off = 4; off; off >>= 1) {
        const unsigned long long o = __shfl_xor(pk2, off);
        const float x2 = __shfl_xor(fx, off);
        const float y2 = __shfl_xor(fy, off);
        const float z2 = __shfl_xor(fz, off);
        if (o > pk2) { pk2 = o; fx = x2; fy = y2; fz = z2; }  // bit63 -> garbage lanes lose
      }
      if (l == 0) {
        winx = fx; winy = fy; winz = fz;
        if (sub == 0) selg[t] = (int)(0xFFFFFFFFu - (unsigned)(pk2 & 0xFFFFFFFFull));
      }
    }
    __syncthreads();
    lx = winx; ly = winy; lz = winz;   // LDS broadcast, no global load
  }
}

// ---------- per-branch kmeans kernel (512 threads; round-7-verified code) ----------
__global__ __launch_bounds__(TPB) void branch_kernel(const float* __restrict__ logits,
                                                     const float* __restrict__ logits1,
                                                     const float* __restrict__ pfirst,
                                                     const float* __restrict__ psec,
                                                     float* __restrict__ feaT_base,
                                                     float* __restrict__ accum) {
  const int b = blockIdx.x;                  // 0,1 -> logits/p0first; 2,3 -> logits1/p0sec
  const float* fea_all = ((b < 2) ? logits : logits1) + (size_t)(b & 1) * N_PTS * CD;
  const float* pos     = ((b < 2) ? pfirst : psec) + (size_t)(b & 1) * N_PTS * 3;
  float* feaT = feaT_base + (size_t)b * NS * CD;   // [CD][NS] transposed sampled features
  const int* selg = (const int*)feaT;              // overlay: read fully before feaT writes

  __shared__ Sm sm;
  extern __shared__ char dynraw[];
  const int tid = threadIdx.x, w = tid >> 6, l = tid & 63;

  // load FPS selection (must complete before any feaT write - barrier below)
  for (int i = tid; i < NS; i += TPB) sm.sel[i] = selg[i];
  __syncthreads();

  // ================= gather sampled pos into LDS =================
  float* pos_s = (float*)dynraw;             // [NS*3] 0..24576
  float* stag  = (float*)(dynraw + 24576);   // [64][257] = 65792 B -> 24576..90368
  float* wbuf  = (float*)(dynraw + 24576);   // 40960 B, reused after transpose
  float* mdbuf = (float*)(dynraw + 98304);   // [NS] 8192 B -> 98304..106496 (clear of stag)
  for (int i = tid; i < NS; i += TPB) {
    const int s = sm.sel[i];
    pos_s[3 * i] = pos[3 * s]; pos_s[3 * i + 1] = pos[3 * s + 1]; pos_s[3 * i + 2] = pos[3 * s + 2];
  }

  // ================= gather + transpose sampled features -> feaT =================
  for (int tile = 0; tile < NS; tile += 64) {
    __syncthreads();
    for (int rr = w; rr < 64; rr += 8) {
      const int srow = sm.sel[tile + rr];
      const float4 v = *(const float4*)&fea_all[(size_t)srow * CD + 4 * l];
      float* dst = &stag[rr * 257 + 4 * l];
      dst[0] = v.x; dst[1] = v.y; dst[2] = v.z; dst[3] = v.w;
    }
    __syncthreads();
    for (int dd = 0; dd < 32; dd++) {
      const int dim = w * 32 + dd;
      feaT[(size_t)dim * NS + tile + l] = stag[l * 257 + dim];
    }
  }
  __syncthreads();

  // ================= initial centroids (greedy, on positions) =================
  if (tid == 0) { sm.c3[0][0] = pos_s[0]; sm.c3[0][1] = pos_s[1]; sm.c3[0][2] = pos_s[2]; }
  __syncthreads();
  for (int k = 1; k < KC; k++) {
    float lv = -1.f; int li = 0x7fffffff;
    #pragma unroll
    for (int r = 0; r < 4; r++) {
      const int i = 4 * tid + r;
      const float x = pos_s[3 * i], y = pos_s[3 * i + 1], z = pos_s[3 * i + 2];
      float a = 0.f;
      for (int j = 0; j < k; j++) {
        const float dx = x - sm.c3[j][0], dy = y - sm.c3[j][1], dz = z - sm.c3[j][2];
        a += dx * dx + dy * dy + dz * dz;
      }
      if (a > lv) { lv = a; li = i; }
    }
    float bv; int bi;
    block_argmax(lv, li, sm, bv, bi);
    if (tid == 0) { sm.c3[k][0] = pos_s[3 * bi]; sm.c3[k][1] = pos_s[3 * bi + 1]; sm.c3[k][2] = pos_s[3 * bi + 2]; }
    __syncthreads();
  }

  // ================= one kmeans step on positions =================
  {
    float a3[KC][3]; float cn[KC];
    #pragma unroll
    for (int k = 0; k < KC; k++) { a3[k][0] = 0.f; a3[k][1] = 0.f; a3[k][2] = 0.f; cn[k] = 0.f; }
    #pragma unroll
    for (int r = 0; r < 4; r++) {
      const int i = 4 * tid + r;
      const float x = pos_s[3 * i], y = pos_s[3 * i + 1], z = pos_s[3 * i + 2];
      float best = FLT_MAX; int bk = 0;
      #pragma unroll
      for (int k = 0; k < KC; k++) {
        const float dx = x - sm.c3[k][0], dy = y - sm.c3[k][1], dz = z - sm.c3[k][2];
        const float s = dx * dx + dy * dy + dz * dz;
        if (s < best) { best = s; bk = k; }
      }
      sm.idx[i] = bk;
      #pragma unroll
      for (int k = 0; k < KC; k++) {
        const float m = (bk == k) ? 1.f : 0.f;
        a3[k][0] += m * x; a3[k][1] += m * y; a3[k][2] += m * z; cn[k] += m;
      }
    }
    reduce_counts(sm, cn);
    #pragma unroll
    for (int k = 0; k < KC; k++) {
      #pragma unroll
      for (int c = 0; c < 3; c++) {
        float s = a3[k][c];
        #pragma unroll
        for (int off = 32; off; off >>= 1) s += __shfl_xor(s, off);
        a3[k][c] = s;
      }
    }
    __syncthreads();
    if (l == 0) {
      #pragma unroll
      for (int k = 0; k < KC; k++) {
        wbuf[w * 16 + k * 3 + 0] = a3[k][0];
        wbuf[w * 16 + k * 3 + 1] = a3[k][1];
        wbuf[w * 16 + k * 3 + 2] = a3[k][2];
      }
    }
    __syncthreads();
    if (tid == 0) {
      for (int k = 0; k < KC; k++)
        for (int c = 0; c < 3; c++) {
          float s = 0.f;
          for (int g = 0; g < 8; g++) s += wbuf[g * 16 + k * 3 + c];
          sm.c3[k][c] = s / fmaxf(sm.cnt[k], 1.f);
        }
    }
    __syncthreads();
  }
  float psum = 0.f;
  #pragma unroll
  for (int r = 0; r < 4; r++) {
    const int i = 4 * tid + r; const int k = sm.idx[i];
    const float dx = pos_s[3 * i] - sm.c3[k][0];
    const float dy = pos_s[3 * i + 1] - sm.c3[k][1];
    const float dz = pos_s[3 * i + 2] - sm.c3[k][2];
    psum += dx * dx + dy * dy + dz * dz;
  }
  const float sse_n = sqrtf(block_sum(psum, sm));
  {  // empty-cluster fixup (positions)
    int nmask = 0;
    #pragma unroll
    for (int k = 0; k < KC; k++) nmask |= (sm.cnt[k] == 0.f) ? (1 << k) : 0;
    if (nmask) {
      #pragma unroll
      for (int r = 0; r < 4; r++) {
        const int i = 4 * tid + r;
        const float x = pos_s[3 * i], y = pos_s[3 * i + 1], z = pos_s[3 * i + 2];
        float s = 0.f;
        for (int k = 0; k < KC; k++) {
          if (sm.cnt[k] > 0.f) {
            const float dx = x - sm.c3[k][0], dy = y - sm.c3[k][1], dz = z - sm.c3[k][2];
            s += sqrtf(dx * dx + dy * dy + dz * dz + 1e-12f);
          }
        }
        mdbuf[i] = s;
      }
      __syncthreads();
      top5(sm, mdbuf);
      if (tid == 0) {
        int cum = 0;
        for (int k = 0; k < KC; k++) {
          if (sm.cnt[k] == 0.f) {
            const int rk = (cum < KC) ? cum : (KC - 1);
            const int src = sm.far5[rk];
            sm.c3[k][0] = pos_s[3 * src]; sm.c3[k][1] = pos_s[3 * src + 1]; sm.c3[k][2] = pos_s[3 * src + 2];
            cum++;
          }
        }
      }
      __syncthreads();
    }
  }

  // ================= kmeans on features =================
  assign3(sm, feaT);
  float sse_fin = centroids_fea(sm, wbuf, mdbuf, fea_all, feaT);
  float sse_pre = sse_fin;
  bool done = fabsf(sse_fin) < TOLV;
  for (int it = 1; it < MAX_IT && !done; it++) {
    assign_full(sm, feaT);
    const float s2 = centroids_fea(sm, wbuf, mdbuf, fea_all, feaT);
    sse_fin = s2;
    done = fabsf(s2 - sse_pre) < TOLV;
    sse_pre = s2;
  }
  if (tid == 0) atomicAdd(&accum[1], sse_n + sse_fin);
}

// ---------- global point loss (cosine similarity) ----------
__global__ __launch_bounds__(256) void gp_kernel(const float* __restrict__ A,
                                                 const float* __restrict__ B,
                                                 float* __restrict__ accum) {
  __shared__ float bacc;
  const int tid = threadIdx.x, l = tid & 63, w = tid >> 6;
  if (tid == 0) bacc = 0.f;
  __syncthreads();
  const int gw = blockIdx.x * 4 + w;
  const int NW = gridDim.x * 4;
  float lsum = 0.f;
  for (int p = gw; p < 65536; p += NW) {
    const float4 a = *(const float4*)&A[(size_t)p * CD + 4 * l];
    const float4 b = *(const float4*)&B[(size_t)p * CD + 4 * l];
    float ab = a.x * b.x + a.y * b.y + a.z * b.z + a.w * b.w;
    float aa = a.x * a.x + a.y * a.y + a.z * a.z + a.w * a.w;
    float bb = b.x * b.x + b.y * b.y + b.z * b.z + b.w * b.w;
    #pragma unroll
    for (int off = 32; off; off >>= 1) {
      ab += __shfl_xor(ab, off); aa += __shfl_xor(aa, off); bb += __shfl_xor(bb, off);
    }
    if (l == 0) lsum += ab / fmaxf(sqrtf(aa) * sqrtf(bb), 1e-8f);
  }
  if (l == 0) atomicAdd(&bacc, lsum);
  __syncthreads();
  if (tid == 0) atomicAdd(&accum[0], bacc);
}

__global__ void fin_kernel(const float* __restrict__ accum, float* __restrict__ out) {
  out[0] = -accum[0] / 65536.0f + accum[1];
}

extern "C" void kernel_launch(void* const* d_in, const int* in_sizes, int n_in,
                              void* d_out, int out_size, void* d_ws, size_t ws_size,
                              hipStream_t stream) {
  const float* logits  = (const float*)d_in[0];
  const float* logits1 = (const float*)d_in[1];
  const float* pfirst  = (const float*)d_in[2];
  const float* psec    = (const float*)d_in[3];
  float* out = (float*)d_out;
  float* wsf = (float*)d_ws;
  float* accum = wsf;                                  // [0]=sum of cos, [1]=sum of sse
  unsigned long long* cand = (unsigned long long*)(wsf + 16);      // 4*NS*8 u64 = 512 KB
  float4* cpos = (float4*)(wsf + 16 + 4 * NS * NB_F * 2);          // 4*NS*8 float4 = 1 MB
  float* feaT = wsf + 16 + 4 * NS * NB_F * 2 + 4 * NS * NB_F * 4;  // 8 MB; 16B-aligned

  static std::once_flag once;
  std::call_once(once, []() {
    (void)hipFuncSetAttribute((const void*)branch_kernel,
                              hipFuncAttributeMaxDynamicSharedMemorySize, DYN_K);
    (void)hipGetLastError();
  });

  // zero accum + ALL cand flag slots (fresh slots each launch -> poll is ABA-free;
  // cpos needs no zeroing - guarded by the cand release/acquire handshake)
  (void)hipMemsetAsync(wsf, 0, 64 + (size_t)4 * NS * NB_F * 8, stream);
  gp_kernel<<<1024, 256, 0, stream>>>(logits, logits1, accum);
  fps_kernel<<<4 * NB_F, TPB_F, 0, stream>>>(pfirst, psec, (int*)feaT, cand, cpos);
  branch_kernel<<<4, TPB, DYN_K, stream>>>(logits, logits1, pfirst, psec, feaT, accum);
  fin_kernel<<<1, 1, 0, stream>>>(accum, out);
}

// Round 11
// 6434.905 us; speedup vs baseline: 2.9696x; 1.5632x over previous
//
#include <hip/hip_runtime.h>
#include <math.h>
#include <float.h>
#include <mutex>

// Problem constants (match reference)
#define N_PTS  32768
#define NS     2048      // N_PTS/16 downsample
#define CD     256
#define KC     5
#define TPB    512       // kmeans kernel threads/block
#define TPB_F  512       // FPS kernel threads/block
#define NB_F   8         // FPS blocks per branch (round-7-verified)
#define NB_K   8         // kmeans blocks per branch (distributed kmeans)
#define LPTS   256       // NS/NB_K local sampled points per kmeans block
#define APAY_N 1285      // A-payload floats: counts[5] + sums[5*256]
#define MAX_IT 100
#define TOLV   1e-3f
#define DYN_K  131072    // kmeans dyn LDS: pos_s(24576) + stag/wbuf + mdbuf(@98304)

struct Sm {
  int   sel[NS];        // FPS-selected indices into the 32768 points (full copy)
  int   idx[NS];        // cluster assignment (position phase: 2048; feature phase: local 256)
  float cm[KC][CD];     // feature-space centroids (globally reduced, identical per block)
  float cc2h[KC];       // 0.5*|c|^2
  float c3[KC][3];      // position-space centroids
  float cnt[KC];        // counts (position phase: global; feature phase: LOCAL partials)
  float wc[8][KC];      // per-wave count partials
  float redf[8];
  int   redi[8];
  int   far5[KC];
};

// ---------- block reductions (512 threads = 8 waves) ----------
__device__ __forceinline__ void block_argmax(float v, int i, Sm& sm, float& bv, int& bi) {
  #pragma unroll
  for (int off = 32; off; off >>= 1) {
    float v2 = __shfl_xor(v, off);
    int   i2 = __shfl_xor(i, off);
    if (v2 > v || (v2 == v && i2 < i)) { v = v2; i = i2; }
  }
  __syncthreads();
  if ((threadIdx.x & 63) == 0) { sm.redf[threadIdx.x >> 6] = v; sm.redi[threadIdx.x >> 6] = i; }
  __syncthreads();
  bv = sm.redf[0]; bi = sm.redi[0];
  #pragma unroll
  for (int g = 1; g < 8; g++) {
    float v2 = sm.redf[g]; int i2 = sm.redi[g];
    if (v2 > bv || (v2 == bv && i2 < bi)) { bv = v2; bi = i2; }
  }
}

__device__ __forceinline__ float block_sum(float v, Sm& sm) {
  #pragma unroll
  for (int off = 32; off; off >>= 1) v += __shfl_xor(v, off);
  __syncthreads();
  if ((threadIdx.x & 63) == 0) sm.redf[threadIdx.x >> 6] = v;
  __syncthreads();
  float s = 0.f;
  #pragma unroll
  for (int g = 0; g < 8; g++) s += sm.redf[g];
  return s;  // identical in all threads
}

__device__ __forceinline__ void reduce_counts(Sm& sm, float cn[KC]) {
  const int w = threadIdx.x >> 6, l = threadIdx.x & 63;
  #pragma unroll
  for (int k = 0; k < KC; k++) {
    float s = cn[k];
    #pragma unroll
    for (int off = 32; off; off >>= 1) s += __shfl_xor(s, off);
    cn[k] = s;
  }
  __syncthreads();
  if (l == 0) {
    #pragma unroll
    for (int k = 0; k < KC; k++) sm.wc[w][k] = cn[k];
  }
  __syncthreads();
  if (threadIdx.x == 0) {
    #pragma unroll
    for (int k = 0; k < KC; k++) {
      float s = 0.f;
      #pragma unroll
      for (int g = 0; g < 8; g++) s += sm.wc[g][k];
      sm.cnt[k] = s;
    }
  }
  __syncthreads();
}

__device__ void top5(Sm& sm, float* mdbuf) {   // position-phase (2048-wide) top5
  for (int r5 = 0; r5 < KC; r5++) {
    float lv = -1.f; int li = 0x7fffffff;
    #pragma unroll
    for (int r = 0; r < 4; r++) {
      const int i = 4 * threadIdx.x + r;
      const float v = mdbuf[i];
      if (v > lv) { lv = v; li = i; }
    }
    float bv; int bi;
    block_argmax(lv, li, sm, bv, bi);
    if (threadIdx.x == 0) { sm.far5[r5] = bi; mdbuf[bi] = -2.f; }
    __syncthreads();
  }
}

// ---------- distributed kmeans: local assignment over LPTS points ----------
// one point per thread (tid<256): per-point j-ascending FP chains identical to the
// verified single-block kernel.
__device__ void assign3_local(Sm& sm, const float* feaT, int base) {
  const int tid = threadIdx.x;
  float cn[KC] = {0.f, 0.f, 0.f, 0.f, 0.f};
  if (tid < LPTS) {
    const float x0 = feaT[0 * NS + base + tid];
    const float x1 = feaT[1 * NS + base + tid];
    const float x2 = feaT[2 * NS + base + tid];
    float best = FLT_MAX; int bk = 0;
    #pragma unroll
    for (int k = 0; k < KC; k++) {
      const float d0 = x0 - sm.c3[k][0];
      const float d1 = x1 - sm.c3[k][1];
      const float d2 = x2 - sm.c3[k][2];
      const float s = d0 * d0 + d1 * d1 + d2 * d2;
      if (s < best) { best = s; bk = k; }
    }
    sm.idx[tid] = bk;
    cn[bk] = 1.f;
  }
  reduce_counts(sm, cn);   // sm.cnt = LOCAL counts (published in A)
}

__device__ void assign_full_local(Sm& sm, const float* feaT, int base) {
  const int tid = threadIdx.x;
  float cn[KC] = {0.f, 0.f, 0.f, 0.f, 0.f};
  if (tid < LPTS) {
    float dot[KC] = {0.f, 0.f, 0.f, 0.f, 0.f};
    for (int j = 0; j < CD; j++) {
      const float x = feaT[(size_t)j * NS + base + tid];
      #pragma unroll
      for (int k = 0; k < KC; k++) dot[k] += x * sm.cm[k][j];
    }
    float best = dot[0] - sm.cc2h[0]; int bk = 0;
    #pragma unroll
    for (int k = 1; k < KC; k++) {
      const float s = dot[k] - sm.cc2h[k];
      if (s > best) { best = s; bk = k; }
    }
    sm.idx[tid] = bk;
    cn[bk] = 1.f;
  }
  reduce_counts(sm, cn);
}

// ---------- distributed kmeans iteration core ----------
// A-exchange: partial counts+sums (all-to-all, redundant reduction -> identical cm).
// C-exchange: sse partials + (rare) local top5 for empty-cluster fixup.
// Seq-flag protocol: payload stores; __threadfence; __syncthreads; release-store flag=n;
// wave-0 lanes poll flags==n; barrier; bulk-read payloads (acquire-ordered).
// Slot reuse is safe: block b writes A(n+1) only after C-poll(n), which requires all
// blocks published C(n), which happens only after they finished reading A(n).
__device__ float iter_core(Sm& sm, float* wbuf, float* mdbuf,
                           const float* fea_all, const float* feaT,
                           float* Apay, unsigned* Aflag, float* Cpay, unsigned* Cflag,
                           int base, int sub, unsigned n) {
  const int tid = threadIdx.x, w = tid >> 6, l = tid & 63;
  // per-wave partial centroid sums: wave w owns local points [w*32, w*32+32)
  float4 acc[KC];
  #pragma unroll
  for (int k = 0; k < KC; k++) acc[k] = make_float4(0.f, 0.f, 0.f, 0.f);
  #pragma unroll 4
  for (int ii = 0; ii < 32; ii++) {
    const int li = (w << 5) + ii;
    const int k = __builtin_amdgcn_readfirstlane(sm.idx[li]);
    const float4 v = *(const float4*)&fea_all[(size_t)sm.sel[base + li] * CD + 4 * l];
    switch (k) {
      case 0: acc[0].x += v.x; acc[0].y += v.y; acc[0].z += v.z; acc[0].w += v.w; break;
      case 1: acc[1].x += v.x; acc[1].y += v.y; acc[1].z += v.z; acc[1].w += v.w; break;
      case 2: acc[2].x += v.x; acc[2].y += v.y; acc[2].z += v.z; acc[2].w += v.w; break;
      case 3: acc[3].x += v.x; acc[3].y += v.y; acc[3].z += v.z; acc[3].w += v.w; break;
      default: acc[4].x += v.x; acc[4].y += v.y; acc[4].z += v.z; acc[4].w += v.w; break;
    }
  }
  #pragma unroll
  for (int k = 0; k < KC; k++) *(float4*)&wbuf[(w * KC + k) * CD + 4 * l] = acc[k];
  __syncthreads();
  // publish A = {local counts[5], local sums[1280]}
  float* myA = Apay + sub * APAY_N;
  for (int e = tid; e < APAY_N; e += TPB) {
    float s;
    if (e < KC) s = sm.cnt[e];
    else {
      s = 0.f;
      #pragma unroll
      for (int g = 0; g < 8; g++) s += wbuf[g * (KC * CD) + (e - KC)];
    }
    myA[e] = s;
  }
  __threadfence();
  __syncthreads();
  if (tid == 0) __hip_atomic_store(&Aflag[sub], n, __ATOMIC_RELEASE, __HIP_MEMORY_SCOPE_AGENT);
  if (w == 0 && l < NB_K) {
    while (__hip_atomic_load(&Aflag[l], __ATOMIC_ACQUIRE, __HIP_MEMORY_SCOPE_AGENT) != n)
      __builtin_amdgcn_s_sleep(1);
  }
  __syncthreads();
  // reduce A (redundant, identical everywhere); b ascending = points ascending
  float cntk[KC];
  #pragma unroll
  for (int k = 0; k < KC; k++) {
    float s = 0.f;
    for (int b = 0; b < NB_K; b++) s += Apay[b * APAY_N + k];
    cntk[k] = s;
  }
  for (int e = tid; e < KC * CD; e += TPB) {
    float s = 0.f;
    for (int b = 0; b < NB_K; b++) s += Apay[b * APAY_N + KC + e];
    (&sm.cm[0][0])[e] = s / fmaxf(cntk[e >> 8], 1.f);
  }
  __syncthreads();
  // local sse partial over first 3 feature dims (pre-fixup cm)
  float contrib = 0.f;
  if (tid < LPTS) {
    const float x0 = feaT[0 * NS + base + tid];
    const float x1 = feaT[1 * NS + base + tid];
    const float x2 = feaT[2 * NS + base + tid];
    const int k = sm.idx[tid];
    const float d0 = x0 - sm.cm[k][0], d1 = x1 - sm.cm[k][1], d2 = x2 - sm.cm[k][2];
    contrib = d0 * d0 + d1 * d1 + d2 * d2;
  }
  const float lps = block_sum(contrib, sm);
  // empty-cluster metric + local top5 (rare; nmask identical across blocks)
  int nmask = 0;
  #pragma unroll
  for (int k = 0; k < KC; k++) nmask |= (cntk[k] == 0.f) ? (1 << k) : 0;
  float f5v[KC] = {0.f, 0.f, 0.f, 0.f, 0.f};
  int   f5i[KC] = {0, 0, 0, 0, 0};
  if (nmask) {
    if (tid < LPTS) {
      float dd[KC] = {0.f, 0.f, 0.f, 0.f, 0.f};
      for (int j = 0; j < CD; j++) {
        const float x = feaT[(size_t)j * NS + base + tid];
        #pragma unroll
        for (int k = 0; k < KC; k++) { const float d = x - sm.cm[k][j]; dd[k] += d * d; }
      }
      float s = 0.f;
      #pragma unroll
      for (int k = 0; k < KC; k++)
        if (cntk[k] > 0.f) s += sqrtf(fmaxf(dd[k], 0.f) + 1e-12f);
      mdbuf[tid] = s;
    }
    __syncthreads();
    for (int r5 = 0; r5 < KC; r5++) {
      const float lv = (tid < LPTS) ? mdbuf[tid] : -1.f;
      const int   li = (tid < LPTS) ? (base + tid) : 0x7fffffff;
      float bv; int bi;
      block_argmax(lv, li, sm, bv, bi);
      f5v[r5] = bv; f5i[r5] = bi;           // identical in all threads
      if (tid < LPTS && base + tid == bi) mdbuf[tid] = -2.f;
      __syncthreads();
    }
  }
  // publish C = {psum, top5 values, top5 global indices (bitcast)}
  float* myC = Cpay + sub * 16;
  if (tid == 0) {
    myC[0] = lps;
    #pragma unroll
    for (int r = 0; r < KC; r++) { myC[1 + r] = f5v[r]; myC[6 + r] = __int_as_float(f5i[r]); }
  }
  __threadfence();
  __syncthreads();
  if (tid == 0) __hip_atomic_store(&Cflag[sub], n, __ATOMIC_RELEASE, __HIP_MEMORY_SCOPE_AGENT);
  if (w == 0 && l < NB_K) {
    while (__hip_atomic_load(&Cflag[l], __ATOMIC_ACQUIRE, __HIP_MEMORY_SCOPE_AGENT) != n)
      __builtin_amdgcn_s_sleep(1);
  }
  __syncthreads();
  // read C: sse; merged exact top5 (value desc, index asc == lax.top_k) + fixup
  float ps = 0.f;
  for (int b = 0; b < NB_K; b++) ps += Cpay[b * 16];
  const float sse = sqrtf(ps);
  if (nmask) {
    unsigned long long used = 0ull;
    int farg[KC];
    for (int r5 = 0; r5 < KC; r5++) {
      float bv = -3.f; int bi = 0x7fffffff; int bs = 0;
      for (int s = 0; s < NB_K * KC; s++) {
        if (used & (1ull << s)) continue;
        const float v = Cpay[(s / KC) * 16 + 1 + (s % KC)];
        const int   i = __float_as_int(Cpay[(s / KC) * 16 + 6 + (s % KC)]);
        if (v > bv || (v == bv && i < bi)) { bv = v; bi = i; bs = s; }
      }
      used |= (1ull << bs);
      farg[r5] = bi;
    }
    int cum = 0;
    for (int k = 0; k < KC; k++) {     // uniform across threads and blocks
      if (cntk[k] == 0.f) {
        const int rk = (cum < KC) ? cum : (KC - 1);
        const int row = sm.sel[farg[rk]];
        for (int d = tid; d < CD; d += TPB) sm.cm[k][d] = fea_all[(size_t)row * CD + d];
        cum++;
      }
    }
    __syncthreads();
  }
  // cc2h (after fixup, for next assignment)
  if (tid < KC * 64) {
    const float4 c = *(const float4*)&sm.cm[w][4 * l];
    float s = c.x * c.x + c.y * c.y + c.z * c.z + c.w * c.w;
    #pragma unroll
    for (int off = 32; off; off >>= 1) s += __shfl_xor(s, off);
    if (l == 0) sm.cc2h[w] = 0.5f * s;
  }
  __syncthreads();
  return sse;
}

// ---------- FPS kernel: EXACT round-7 code (measured 5437 us) ----------
// Only change: sel output goes to a dedicated workspace array (the feaT-slab overlay
// is no longer safe: 8 kmeans blocks now write disjoint feaT column slices).
__global__ __launch_bounds__(TPB_F) void fps_kernel(const float* __restrict__ pfirst,
                                                    const float* __restrict__ psec,
                                                    int* __restrict__ sel_base,
                                                    unsigned long long* __restrict__ cand) {
  const int br = blockIdx.x >> 3, sub = blockIdx.x & 7;
  const float* pos = ((br < 2) ? pfirst : psec) + (size_t)(br & 1) * N_PTS * 3;
  int* selg = sel_base + (size_t)br * NS;
  unsigned long long* mycand = cand + (size_t)br * NS * NB_F;
  __shared__ float redf[8];
  __shared__ int   redi[8];
  __shared__ int   winLDS;
  const int tid = threadIdx.x, w = tid >> 6, l = tid & 63;
  const int base = sub * 4096;

  float px[8], py[8], pz[8], dd[8];          // 32 registers, static indices only
  #pragma unroll
  for (int k = 0; k < 8; k++) {
    const int p = base + tid + k * TPB_F;
    px[k] = pos[3 * p]; py[k] = pos[3 * p + 1]; pz[k] = pos[3 * p + 2];
    dd[k] = 1e10f;
  }
  if (sub == 0 && tid == 0) selg[0] = 0;
  float lx = pos[0], ly = pos[1], lz = pos[2];

  for (int t = 1; t < NS; t++) {
    float bv = -1.f; int bi = 0x7fffffff;
    #pragma unroll
    for (int k = 0; k < 8; k++) {
      const float dx = px[k] - lx, dy = py[k] - ly, dz = pz[k] - lz;
      const float dist = dx * dx + dy * dy + dz * dz;
      dd[k] = fminf(dd[k], dist);
      if (dd[k] > bv) { bv = dd[k]; bi = base + tid + k * TPB_F; }
    }
    #pragma unroll
    for (int off = 32; off; off >>= 1) {
      const float v2 = __shfl_xor(bv, off);
      const int   i2 = __shfl_xor(bi, off);
      if (v2 > bv || (v2 == bv && i2 < bi)) { bv = v2; bi = i2; }
    }
    if (l == 0) { redf[w] = bv; redi[w] = bi; }
    __syncthreads();
    if (tid == 0) {
      float cv = redf[0]; int ci = redi[0];
      #pragma unroll
      for (int g = 1; g < 8; g++) {
        if (redf[g] > cv || (redf[g] == cv && redi[g] < ci)) { cv = redf[g]; ci = redi[g]; }
      }
      const unsigned long long pk = (1ULL << 63)
          | ((unsigned long long)__float_as_uint(cv) << 32)
          | (unsigned long long)(0xFFFFFFFFu - (unsigned)ci);
      __hip_atomic_store(&mycand[(size_t)t * NB_F + sub], pk,
                         __ATOMIC_RELEASE, __HIP_MEMORY_SCOPE_AGENT);
    }
    if (w == 0 && l < NB_F) {
      unsigned long long pk = __hip_atomic_load(&mycand[(size_t)t * NB_F + l],
                                                __ATOMIC_ACQUIRE, __HIP_MEMORY_SCOPE_AGENT);
      while (pk == 0ULL) {
        __builtin_amdgcn_s_sleep(1);
        pk = __hip_atomic_load(&mycand[(size_t)t * NB_F + l],
                               __ATOMIC_ACQUIRE, __HIP_MEMORY_SCOPE_AGENT);
      }
      #pragma unroll
      for (int off = 4; off; off >>= 1) {
        const unsigned long long o = __shfl_xor(pk, off, NB_F);
        pk = (o > pk) ? o : pk;
      }
      if (l == 0) {
        const int gi = (int)(0xFFFFFFFFu - (unsigned)(pk & 0xFFFFFFFFull));
        winLDS = gi;
        if (sub == 0) selg[t] = gi;
      }
    }
    __syncthreads();
    const int gbi = winLDS;
    lx = pos[3 * gbi]; ly = pos[3 * gbi + 1]; lz = pos[3 * gbi + 2];  // bcast, L1/L2-hit
  }
}

// ---------- distributed kmeans kernel: 8 blocks/branch x 512 threads ----------
// Position phase runs redundantly in every block (identical inputs -> identical c3/sse_n,
// no sync). Feature phase distributes the two heavy 2MB/iter streams (assign read of
// feaT; centroid gather of fea_all) across 8 CUs, syncing twice per iteration via the
// seq-flag protocol proven in fps_kernel.
__global__ __launch_bounds__(TPB) void branch_kernel(const float* __restrict__ logits,
                                                     const float* __restrict__ logits1,
                                                     const float* __restrict__ pfirst,
                                                     const float* __restrict__ psec,
                                                     const int* __restrict__ sel_base,
                                                     float* __restrict__ feaT_base,
                                                     float* __restrict__ accum,
                                                     float* __restrict__ apay,
                                                     unsigned* __restrict__ aflag,
                                                     float* __restrict__ cpay,
                                                     unsigned* __restrict__ cflag) {
  const int br = blockIdx.x >> 3, sub = blockIdx.x & 7;
  const float* fea_all = ((br < 2) ? logits : logits1) + (size_t)(br & 1) * N_PTS * CD;
  const float* pos     = ((br < 2) ? pfirst : psec) + (size_t)(br & 1) * N_PTS * 3;
  const int* selg = sel_base + (size_t)br * NS;
  float* feaT = feaT_base + (size_t)br * NS * CD;
  float*    Apay  = apay  + (size_t)br * NB_K * APAY_N;
  unsigned* Aflag = aflag + br * NB_K;
  float*    Cpay  = cpay  + (size_t)br * NB_K * 16;
  unsigned* Cflag = cflag + br * NB_K;
  const int base = sub * LPTS;

  __shared__ Sm sm;
  extern __shared__ char dynraw[];
  const int tid = threadIdx.x, w = tid >> 6, l = tid & 63;

  for (int i = tid; i < NS; i += TPB) sm.sel[i] = selg[i];
  __syncthreads();

  // ================= gather sampled pos into LDS (full 2048, redundant) =========
  float* pos_s = (float*)dynraw;             // [NS*3] 0..24576
  float* stag  = (float*)(dynraw + 24576);   // [64][257] transpose staging
  float* wbuf  = (float*)(dynraw + 24576);   // 40960 B, reused after transpose
  float* mdbuf = (float*)(dynraw + 98304);   // [NS] (position) / [LPTS] (feature)
  for (int i = tid; i < NS; i += TPB) {
    const int s = sm.sel[i];
    pos_s[3 * i] = pos[3 * s]; pos_s[3 * i + 1] = pos[3 * s + 1]; pos_s[3 * i + 2] = pos[3 * s + 2];
  }

  // ================= gather + transpose OWN feature slice -> feaT ===============
  for (int tile = base; tile < base + LPTS; tile += 64) {
    __syncthreads();
    for (int rr = w; rr < 64; rr += 8) {
      const int srow = sm.sel[tile + rr];
      const float4 v = *(const float4*)&fea_all[(size_t)srow * CD + 4 * l];
      float* dst = &stag[rr * 257 + 4 * l];
      dst[0] = v.x; dst[1] = v.y; dst[2] = v.z; dst[3] = v.w;
    }
    __syncthreads();
    for (int dd = 0; dd < 32; dd++) {
      const int dim = w * 32 + dd;
      feaT[(size_t)dim * NS + tile + l] = stag[l * 257 + dim];
    }
  }
  __syncthreads();

  // ================= initial centroids (greedy, positions; redundant) ===========
  if (tid == 0) { sm.c3[0][0] = pos_s[0]; sm.c3[0][1] = pos_s[1]; sm.c3[0][2] = pos_s[2]; }
  __syncthreads();
  for (int k = 1; k < KC; k++) {
    float lv = -1.f; int li = 0x7fffffff;
    #pragma unroll
    for (int r = 0; r < 4; r++) {
      const int i = 4 * tid + r;
      const float x = pos_s[3 * i], y = pos_s[3 * i + 1], z = pos_s[3 * i + 2];
      float a = 0.f;
      for (int j = 0; j < k; j++) {
        const float dx = x - sm.c3[j][0], dy = y - sm.c3[j][1], dz = z - sm.c3[j][2];
        a += dx * dx + dy * dy + dz * dz;
      }
      if (a > lv) { lv = a; li = i; }
    }
    float bv; int bi;
    block_argmax(lv, li, sm, bv, bi);
    if (tid == 0) { sm.c3[k][0] = pos_s[3 * bi]; sm.c3[k][1] = pos_s[3 * bi + 1]; sm.c3[k][2] = pos_s[3 * bi + 2]; }
    __syncthreads();
  }

  // ================= one kmeans step on positions (full 2048, redundant) ========
  {
    float a3[KC][3]; float cn[KC];
    #pragma unroll
    for (int k = 0; k < KC; k++) { a3[k][0] = 0.f; a3[k][1] = 0.f; a3[k][2] = 0.f; cn[k] = 0.f; }
    #pragma unroll
    for (int r = 0; r < 4; r++) {
      const int i = 4 * tid + r;
      const float x = pos_s[3 * i], y = pos_s[3 * i + 1], z = pos_s[3 * i + 2];
      float best = FLT_MAX; int bk = 0;
      #pragma unroll
      for (int k = 0; k < KC; k++) {
        const float dx = x - sm.c3[k][0], dy = y - sm.c3[k][1], dz = z - sm.c3[k][2];
        const float s = dx * dx + dy * dy + dz * dz;
        if (s < best) { best = s; bk = k; }
      }
      sm.idx[i] = bk;
      #pragma unroll
      for (int k = 0; k < KC; k++) {
        const float m = (bk == k) ? 1.f : 0.f;
        a3[k][0] += m * x; a3[k][1] += m * y; a3[k][2] += m * z; cn[k] += m;
      }
    }
    reduce_counts(sm, cn);
    #pragma unroll
    for (int k = 0; k < KC; k++) {
      #pragma unroll
      for (int c = 0; c < 3; c++) {
        float s = a3[k][c];
        #pragma unroll
        for (int off = 32; off; off >>= 1) s += __shfl_xor(s, off);
        a3[k][c] = s;
      }
    }
    __syncthreads();
    if (l == 0) {
      #pragma unroll
      for (int k = 0; k < KC; k++) {
        wbuf[w * 16 + k * 3 + 0] = a3[k][0];
        wbuf[w * 16 + k * 3 + 1] = a3[k][1];
        wbuf[w * 16 + k * 3 + 2] = a3[k][2];
      }
    }
    __syncthreads();
    if (tid == 0) {
      for (int k = 0; k < KC; k++)
        for (int c = 0; c < 3; c++) {
          float s = 0.f;
          for (int g = 0; g < 8; g++) s += wbuf[g * 16 + k * 3 + c];
          sm.c3[k][c] = s / fmaxf(sm.cnt[k], 1.f);
        }
    }
    __syncthreads();
  }
  float psum = 0.f;
  #pragma unroll
  for (int r = 0; r < 4; r++) {
    const int i = 4 * tid + r; const int k = sm.idx[i];
    const float dx = pos_s[3 * i] - sm.c3[k][0];
    const float dy = pos_s[3 * i + 1] - sm.c3[k][1];
    const float dz = pos_s[3 * i + 2] - sm.c3[k][2];
    psum += dx * dx + dy * dy + dz * dz;
  }
  const float sse_n = sqrtf(block_sum(psum, sm));
  {  // empty-cluster fixup (positions, full 2048, redundant)
    int nmask = 0;
    #pragma unroll
    for (int k = 0; k < KC; k++) nmask |= (sm.cnt[k] == 0.f) ? (1 << k) : 0;
    if (nmask) {
      #pragma unroll
      for (int r = 0; r < 4; r++) {
        const int i = 4 * tid + r;
        const float x = pos_s[3 * i], y = pos_s[3 * i + 1], z = pos_s[3 * i + 2];
        float s = 0.f;
        for (int k = 0; k < KC; k++) {
          if (sm.cnt[k] > 0.f) {
            const float dx = x - sm.c3[k][0], dy = y - sm.c3[k][1], dz = z - sm.c3[k][2];
            s += sqrtf(dx * dx + dy * dy + dz * dz + 1e-12f);
          }
        }
        mdbuf[i] = s;
      }
      __syncthreads();
      top5(sm, mdbuf);
      if (tid == 0) {
        int cum = 0;
        for (int k = 0; k < KC; k++) {
          if (sm.cnt[k] == 0.f) {
            const int rk = (cum < KC) ? cum : (KC - 1);
            const int src = sm.far5[rk];
            sm.c3[k][0] = pos_s[3 * src]; sm.c3[k][1] = pos_s[3 * src + 1]; sm.c3[k][2] = pos_s[3 * src + 2];
            cum++;
          }
        }
      }
      __syncthreads();
    }
  }

  // ================= distributed kmeans on features =================
  assign3_local(sm, feaT, base);
  float sse_fin = iter_core(sm, wbuf, mdbuf, fea_all, feaT,
                            Apay, Aflag, Cpay, Cflag, base, sub, 1u);
  float sse_pre = sse_fin;
  bool done = fabsf(sse_fin) < TOLV;
  for (int it = 1; it < MAX_IT && !done; it++) {
    assign_full_local(sm, feaT, base);
    const float s2 = iter_core(sm, wbuf, mdbuf, fea_all, feaT,
                               Apay, Aflag, Cpay, Cflag, base, sub, (unsigned)(it + 1));
    sse_fin = s2;
    done = fabsf(s2 - sse_pre) < TOLV;
    sse_pre = s2;
  }
  if (sub == 0 && tid == 0) atomicAdd(&accum[1], sse_n + sse_fin);
}

// ---------- global point loss (cosine similarity) ----------
__global__ __launch_bounds__(256) void gp_kernel(const float* __restrict__ A,
                                                 const float* __restrict__ B,
                                                 float* __restrict__ accum) {
  __shared__ float bacc;
  const int tid = threadIdx.x, l = tid & 63, w = tid >> 6;
  if (tid == 0) bacc = 0.f;
  __syncthreads();
  const int gw = blockIdx.x * 4 + w;
  const int NW = gridDim.x * 4;
  float lsum = 0.f;
  for (int p = gw; p < 65536; p += NW) {
    const float4 a = *(const float4*)&A[(size_t)p * CD + 4 * l];
    const float4 b = *(const float4*)&B[(size_t)p * CD + 4 * l];
    float ab = a.x * b.x + a.y * b.y + a.z * b.z + a.w * b.w;
    float aa = a.x * a.x + a.y * a.y + a.z * a.z + a.w * a.w;
    float bb = b.x * b.x + b.y * b.y + b.z * b.z + b.w * b.w;
    #pragma unroll
    for (int off = 32; off; off >>= 1) {
      ab += __shfl_xor(ab, off); aa += __shfl_xor(aa, off); bb += __shfl_xor(bb, off);
    }
    if (l == 0) lsum += ab / fmaxf(sqrtf(aa) * sqrtf(bb), 1e-8f);
  }
  if (l == 0) atomicAdd(&bacc, lsum);
  __syncthreads();
  if (tid == 0) atomicAdd(&accum[0], bacc);
}

__global__ void fin_kernel(const float* __restrict__ accum, float* __restrict__ out) {
  out[0] = -accum[0] / 65536.0f + accum[1];
}

extern "C" void kernel_launch(void* const* d_in, const int* in_sizes, int n_in,
                              void* d_out, int out_size, void* d_ws, size_t ws_size,
                              hipStream_t stream) {
  const float* logits  = (const float*)d_in[0];
  const float* logits1 = (const float*)d_in[1];
  const float* pfirst  = (const float*)d_in[2];
  const float* psec    = (const float*)d_in[3];
  float* out = (float*)d_out;
  float* wsf = (float*)d_ws;
  // workspace layout (float offsets):
  float* accum = wsf;                                          // [0..16)
  int* selg = (int*)(wsf + 16);                                // 4*NS ints        @16
  unsigned long long* cand = (unsigned long long*)(wsf + 16 + 4 * NS);  // @8208 (byte%8==0)
  unsigned* aflag = (unsigned*)(wsf + 139280);                 // after cand (131072 floats)
  unsigned* cflag = (unsigned*)(wsf + 139312);
  float* apay = wsf + 139344;                                  // 4*8*1285 = 41120 floats
  float* cpay = wsf + 180464;                                  // 4*8*16 = 512 floats
  float* feaT = wsf + 180976;                                  // 4 branches x [CD][NS] = 8 MB

  static std::once_flag once;
  std::call_once(once, []() {
    (void)hipFuncSetAttribute((const void*)branch_kernel,
                              hipFuncAttributeMaxDynamicSharedMemorySize, DYN_K);
    (void)hipGetLastError();
  });

  // zero accum + selg + cand + flags (fresh cand slots + flag seqs start at 0 -> poll ==n
  // with n>=1 is ABA-free; payload regions need no zeroing, guarded by flags)
  (void)hipMemsetAsync(wsf, 0, (size_t)139344 * 4, stream);
  gp_kernel<<<1024, 256, 0, stream>>>(logits, logits1, accum);
  fps_kernel<<<4 * NB_F, TPB_F, 0, stream>>>(pfirst, psec, selg, cand);
  branch_kernel<<<4 * NB_K, TPB, DYN_K, stream>>>(logits, logits1, pfirst, psec,
                                                  selg, feaT, accum,
                                                  apay, aflag, cpay, cflag);
  fin_kernel<<<1, 1, 0, stream>>>(accum, out);
}

// Round 12
// 5769.954 us; speedup vs baseline: 3.3118x; 1.1152x over previous
//
#include <hip/hip_runtime.h>
#include <math.h>
#include <float.h>
#include <mutex>

// Problem constants (match reference)
#define N_PTS  32768
#define NS     2048      // N_PTS/16 downsample
#define CD     256
#define KC     5
#define TPB    512       // kmeans kernel threads/block
#define TPB_F  512       // FPS kernel threads/block
#define NB_F   8         // FPS blocks per branch
#define NB_K   8         // kmeans blocks per branch (distributed kmeans)
#define LPTS   256       // NS/NB_K local sampled points per kmeans block
#define APAY_N 1285      // A-payload floats: counts[5] + sums[5*256]
#define MAX_IT 100
#define TOLV   1e-3f
#define DYN_K  131072    // kmeans dyn LDS: pos_s(24576) + stag/wbuf + mdbuf(@98304)

struct Sm {
  int   sel[NS];        // FPS-selected indices into the 32768 points (full copy)
  int   idx[NS];        // cluster assignment (position phase: 2048; feature phase: local 256)
  float cm[KC][CD];     // feature-space centroids (globally reduced, identical per block)
  float cc2h[KC];       // 0.5*|c|^2
  float c3[KC][3];      // position-space centroids
  float cnt[KC];        // counts (position phase: global; feature phase: LOCAL partials)
  float wc[8][KC];      // per-wave count partials
  float redf[8];
  int   redi[8];
  int   far5[KC];
};

// ---------- block reductions (512 threads = 8 waves) ----------
__device__ __forceinline__ void block_argmax(float v, int i, Sm& sm, float& bv, int& bi) {
  #pragma unroll
  for (int off = 32; off; off >>= 1) {
    float v2 = __shfl_xor(v, off);
    int   i2 = __shfl_xor(i, off);
    if (v2 > v || (v2 == v && i2 < i)) { v = v2; i = i2; }
  }
  __syncthreads();
  if ((threadIdx.x & 63) == 0) { sm.redf[threadIdx.x >> 6] = v; sm.redi[threadIdx.x >> 6] = i; }
  __syncthreads();
  bv = sm.redf[0]; bi = sm.redi[0];
  #pragma unroll
  for (int g = 1; g < 8; g++) {
    float v2 = sm.redf[g]; int i2 = sm.redi[g];
    if (v2 > bv || (v2 == bv && i2 < bi)) { bv = v2; bi = i2; }
  }
}

__device__ __forceinline__ float block_sum(float v, Sm& sm) {
  #pragma unroll
  for (int off = 32; off; off >>= 1) v += __shfl_xor(v, off);
  __syncthreads();
  if ((threadIdx.x & 63) == 0) sm.redf[threadIdx.x >> 6] = v;
  __syncthreads();
  float s = 0.f;
  #pragma unroll
  for (int g = 0; g < 8; g++) s += sm.redf[g];
  return s;  // identical in all threads
}

__device__ __forceinline__ void reduce_counts(Sm& sm, float cn[KC]) {
  const int w = threadIdx.x >> 6, l = threadIdx.x & 63;
  #pragma unroll
  for (int k = 0; k < KC; k++) {
    float s = cn[k];
    #pragma unroll
    for (int off = 32; off; off >>= 1) s += __shfl_xor(s, off);
    cn[k] = s;
  }
  __syncthreads();
  if (l == 0) {
    #pragma unroll
    for (int k = 0; k < KC; k++) sm.wc[w][k] = cn[k];
  }
  __syncthreads();
  if (threadIdx.x == 0) {
    #pragma unroll
    for (int k = 0; k < KC; k++) {
      float s = 0.f;
      #pragma unroll
      for (int g = 0; g < 8; g++) s += sm.wc[g][k];
      sm.cnt[k] = s;
    }
  }
  __syncthreads();
}

__device__ void top5(Sm& sm, float* mdbuf) {   // position-phase (2048-wide) top5
  for (int r5 = 0; r5 < KC; r5++) {
    float lv = -1.f; int li = 0x7fffffff;
    #pragma unroll
    for (int r = 0; r < 4; r++) {
      const int i = 4 * threadIdx.x + r;
      const float v = mdbuf[i];
      if (v > lv) { lv = v; li = i; }
    }
    float bv; int bi;
    block_argmax(lv, li, sm, bv, bi);
    if (threadIdx.x == 0) { sm.far5[r5] = bi; mdbuf[bi] = -2.f; }
    __syncthreads();
  }
}

// ---------- distributed kmeans: local assignment over LPTS points ----------
__device__ void assign3_local(Sm& sm, const float* feaT, int base) {
  const int tid = threadIdx.x;
  float cn[KC] = {0.f, 0.f, 0.f, 0.f, 0.f};
  if (tid < LPTS) {
    const float x0 = feaT[0 * NS + base + tid];
    const float x1 = feaT[1 * NS + base + tid];
    const float x2 = feaT[2 * NS + base + tid];
    float best = FLT_MAX; int bk = 0;
    #pragma unroll
    for (int k = 0; k < KC; k++) {
      const float d0 = x0 - sm.c3[k][0];
      const float d1 = x1 - sm.c3[k][1];
      const float d2 = x2 - sm.c3[k][2];
      const float s = d0 * d0 + d1 * d1 + d2 * d2;
      if (s < best) { best = s; bk = k; }
    }
    sm.idx[tid] = bk;
    cn[bk] = 1.f;
  }
  reduce_counts(sm, cn);   // sm.cnt = LOCAL counts (published in A)
}

__device__ void assign_full_local(Sm& sm, const float* feaT, int base) {
  const int tid = threadIdx.x;
  float cn[KC] = {0.f, 0.f, 0.f, 0.f, 0.f};
  if (tid < LPTS) {
    float dot[KC] = {0.f, 0.f, 0.f, 0.f, 0.f};
    for (int j = 0; j < CD; j++) {
      const float x = feaT[(size_t)j * NS + base + tid];
      #pragma unroll
      for (int k = 0; k < KC; k++) dot[k] += x * sm.cm[k][j];
    }
    float best = dot[0] - sm.cc2h[0]; int bk = 0;
    #pragma unroll
    for (int k = 1; k < KC; k++) {
      const float s = dot[k] - sm.cc2h[k];
      if (s > best) { best = s; bk = k; }
    }
    sm.idx[tid] = bk;
    cn[bk] = 1.f;
  }
  reduce_counts(sm, cn);
}

// ---------- distributed kmeans iteration core (round-11-verified) ----------
__device__ float iter_core(Sm& sm, float* wbuf, float* mdbuf,
                           const float* fea_all, const float* feaT,
                           float* Apay, unsigned* Aflag, float* Cpay, unsigned* Cflag,
                           int base, int sub, unsigned n) {
  const int tid = threadIdx.x, w = tid >> 6, l = tid & 63;
  float4 acc[KC];
  #pragma unroll
  for (int k = 0; k < KC; k++) acc[k] = make_float4(0.f, 0.f, 0.f, 0.f);
  #pragma unroll 4
  for (int ii = 0; ii < 32; ii++) {
    const int li = (w << 5) + ii;
    const int k = __builtin_amdgcn_readfirstlane(sm.idx[li]);
    const float4 v = *(const float4*)&fea_all[(size_t)sm.sel[base + li] * CD + 4 * l];
    switch (k) {
      case 0: acc[0].x += v.x; acc[0].y += v.y; acc[0].z += v.z; acc[0].w += v.w; break;
      case 1: acc[1].x += v.x; acc[1].y += v.y; acc[1].z += v.z; acc[1].w += v.w; break;
      case 2: acc[2].x += v.x; acc[2].y += v.y; acc[2].z += v.z; acc[2].w += v.w; break;
      case 3: acc[3].x += v.x; acc[3].y += v.y; acc[3].z += v.z; acc[3].w += v.w; break;
      default: acc[4].x += v.x; acc[4].y += v.y; acc[4].z += v.z; acc[4].w += v.w; break;
    }
  }
  #pragma unroll
  for (int k = 0; k < KC; k++) *(float4*)&wbuf[(w * KC + k) * CD + 4 * l] = acc[k];
  __syncthreads();
  // publish A = {local counts[5], local sums[1280]}
  float* myA = Apay + sub * APAY_N;
  for (int e = tid; e < APAY_N; e += TPB) {
    float s;
    if (e < KC) s = sm.cnt[e];
    else {
      s = 0.f;
      #pragma unroll
      for (int g = 0; g < 8; g++) s += wbuf[g * (KC * CD) + (e - KC)];
    }
    myA[e] = s;
  }
  __threadfence();
  __syncthreads();
  if (tid == 0) __hip_atomic_store(&Aflag[sub], n, __ATOMIC_RELEASE, __HIP_MEMORY_SCOPE_AGENT);
  if (w == 0 && l < NB_K) {
    while (__hip_atomic_load(&Aflag[l], __ATOMIC_ACQUIRE, __HIP_MEMORY_SCOPE_AGENT) != n)
      __builtin_amdgcn_s_sleep(1);
  }
  __syncthreads();
  // reduce A (redundant, identical everywhere); b ascending = points ascending
  float cntk[KC];
  #pragma unroll
  for (int k = 0; k < KC; k++) {
    float s = 0.f;
    for (int b = 0; b < NB_K; b++) s += Apay[b * APAY_N + k];
    cntk[k] = s;
  }
  for (int e = tid; e < KC * CD; e += TPB) {
    float s = 0.f;
    for (int b = 0; b < NB_K; b++) s += Apay[b * APAY_N + KC + e];
    (&sm.cm[0][0])[e] = s / fmaxf(cntk[e >> 8], 1.f);
  }
  __syncthreads();
  // local sse partial over first 3 feature dims (pre-fixup cm)
  float contrib = 0.f;
  if (tid < LPTS) {
    const float x0 = feaT[0 * NS + base + tid];
    const float x1 = feaT[1 * NS + base + tid];
    const float x2 = feaT[2 * NS + base + tid];
    const int k = sm.idx[tid];
    const float d0 = x0 - sm.cm[k][0], d1 = x1 - sm.cm[k][1], d2 = x2 - sm.cm[k][2];
    contrib = d0 * d0 + d1 * d1 + d2 * d2;
  }
  const float lps = block_sum(contrib, sm);
  // empty-cluster metric + local top5 (rare; nmask identical across blocks)
  int nmask = 0;
  #pragma unroll
  for (int k = 0; k < KC; k++) nmask |= (cntk[k] == 0.f) ? (1 << k) : 0;
  float f5v[KC] = {0.f, 0.f, 0.f, 0.f, 0.f};
  int   f5i[KC] = {0, 0, 0, 0, 0};
  if (nmask) {
    if (tid < LPTS) {
      float dd[KC] = {0.f, 0.f, 0.f, 0.f, 0.f};
      for (int j = 0; j < CD; j++) {
        const float x = feaT[(size_t)j * NS + base + tid];
        #pragma unroll
        for (int k = 0; k < KC; k++) { const float d = x - sm.cm[k][j]; dd[k] += d * d; }
      }
      float s = 0.f;
      #pragma unroll
      for (int k = 0; k < KC; k++)
        if (cntk[k] > 0.f) s += sqrtf(fmaxf(dd[k], 0.f) + 1e-12f);
      mdbuf[tid] = s;
    }
    __syncthreads();
    for (int r5 = 0; r5 < KC; r5++) {
      const float lv = (tid < LPTS) ? mdbuf[tid] : -1.f;
      const int   li = (tid < LPTS) ? (base + tid) : 0x7fffffff;
      float bv; int bi;
      block_argmax(lv, li, sm, bv, bi);
      f5v[r5] = bv; f5i[r5] = bi;           // identical in all threads
      if (tid < LPTS && base + tid == bi) mdbuf[tid] = -2.f;
      __syncthreads();
    }
  }
  // publish C = {psum, top5 values, top5 global indices (bitcast)}
  float* myC = Cpay + sub * 16;
  if (tid == 0) {
    myC[0] = lps;
    #pragma unroll
    for (int r = 0; r < KC; r++) { myC[1 + r] = f5v[r]; myC[6 + r] = __int_as_float(f5i[r]); }
  }
  __threadfence();
  __syncthreads();
  if (tid == 0) __hip_atomic_store(&Cflag[sub], n, __ATOMIC_RELEASE, __HIP_MEMORY_SCOPE_AGENT);
  if (w == 0 && l < NB_K) {
    while (__hip_atomic_load(&Cflag[l], __ATOMIC_ACQUIRE, __HIP_MEMORY_SCOPE_AGENT) != n)
      __builtin_amdgcn_s_sleep(1);
  }
  __syncthreads();
  // read C: sse; merged exact top5 (value desc, index asc == lax.top_k) + fixup
  float ps = 0.f;
  for (int b = 0; b < NB_K; b++) ps += Cpay[b * 16];
  const float sse = sqrtf(ps);
  if (nmask) {
    unsigned long long used = 0ull;
    int farg[KC];
    for (int r5 = 0; r5 < KC; r5++) {
      float bv = -3.f; int bi = 0x7fffffff; int bs = 0;
      for (int s = 0; s < NB_K * KC; s++) {
        if (used & (1ull << s)) continue;
        const float v = Cpay[(s / KC) * 16 + 1 + (s % KC)];
        const int   i = __float_as_int(Cpay[(s / KC) * 16 + 6 + (s % KC)]);
        if (v > bv || (v == bv && i < bi)) { bv = v; bi = i; bs = s; }
      }
      used |= (1ull << bs);
      farg[r5] = bi;
    }
    int cum = 0;
    for (int k = 0; k < KC; k++) {     // uniform across threads and blocks
      if (cntk[k] == 0.f) {
        const int rk = (cum < KC) ? cum : (KC - 1);
        const int row = sm.sel[farg[rk]];
        for (int d = tid; d < CD; d += TPB) sm.cm[k][d] = fea_all[(size_t)row * CD + d];
        cum++;
      }
    }
    __syncthreads();
  }
  // cc2h (after fixup, for next assignment)
  if (tid < KC * 64) {
    const float4 c = *(const float4*)&sm.cm[w][4 * l];
    float s = c.x * c.x + c.y * c.y + c.z * c.z + c.w * c.w;
    #pragma unroll
    for (int off = 32; off; off >>= 1) s += __shfl_xor(s, off);
    if (l == 0) sm.cc2h[w] = 0.5f * s;
  }
  __syncthreads();
  return sse;
}

// ---------- FPS kernel: round-7 protocol + two isolated latency cuts ----------
// Changes vs round-11's verified 5427us kernel (mechanistically independent, both
// traffic-neutral; cpos dirty-line channel from round 9 is NOT reintroduced):
//  1. winner-lane LDS publish + wave-0 shuffle block-reduce (replaces serial tid0
//     8-tuple LDS chain, ~300-800cy off the critical path)
//  2. XCD grouping br=blockIdx&3: each branch's 8 sync agents land on ~2 XCDs
//     under round-robin dispatch -> shorter coherence hops on cand lines (round-9
//     counters: FETCH 10->6MB with this mapping).
// Wave 0 remains the ONLY poller (round-8 lesson); winner pos via read-only
// pos[3*gbi] broadcast load (round-9 lesson: written channels cost more than
// replicated read-only lines).
__global__ __launch_bounds__(TPB_F) void fps_kernel(const float* __restrict__ pfirst,
                                                    const float* __restrict__ psec,
                                                    int* __restrict__ sel_base,
                                                    unsigned long long* __restrict__ cand) {
  const int br = blockIdx.x & 3, sub = blockIdx.x >> 2;   // XCD-grouped mapping
  const float* pos = ((br < 2) ? pfirst : psec) + (size_t)(br & 1) * N_PTS * 3;
  int* selg = sel_base + (size_t)br * NS;
  unsigned long long* mycand = cand + (size_t)br * NS * NB_F;
  __shared__ float redf[8];
  __shared__ int   redi[8];
  __shared__ int   winLDS;
  const int tid = threadIdx.x, w = tid >> 6, l = tid & 63;
  const int base = sub * 4096;

  float px[8], py[8], pz[8], dd[8];          // 32 registers, static indices only
  #pragma unroll
  for (int k = 0; k < 8; k++) {
    const int p = base + tid + k * TPB_F;
    px[k] = pos[3 * p]; py[k] = pos[3 * p + 1]; pz[k] = pos[3 * p + 2];
    dd[k] = 1e10f;
  }
  if (sub == 0 && tid == 0) selg[0] = 0;
  float lx = pos[0], ly = pos[1], lz = pos[2];

  for (int t = 1; t < NS; t++) {
    float bv = -1.f; int bi = 0x7fffffff;
    #pragma unroll
    for (int k = 0; k < 8; k++) {
      const float dx = px[k] - lx, dy = py[k] - ly, dz = pz[k] - lz;
      const float dist = dx * dx + dy * dy + dz * dz;
      dd[k] = fminf(dd[k], dist);
      if (dd[k] > bv) { bv = dd[k]; bi = base + tid + k * TPB_F; }
    }
    const int myi = bi;
    // wave-level (value desc, index asc) argmax
    #pragma unroll
    for (int off = 32; off; off >>= 1) {
      const float v2 = __shfl_xor(bv, off);
      const int   i2 = __shfl_xor(bi, off);
      if (v2 > bv || (v2 == bv && i2 < bi)) { bv = v2; bi = i2; }
    }
    // unique wave-winner lane publishes to LDS (per-lane indices disjoint)
    if (myi == bi) { redf[w] = bv; redi[w] = bi; }
    __syncthreads();
    // wave 0 only: shuffle block-reduce -> publish -> poll -> LDS broadcast
    if (w == 0) {
      float cv = -1.f; int ci = 0x7fffffff;
      if (l < 8) { cv = redf[l]; ci = redi[l]; }
      #pragma unroll
      for (int off = 4; off; off >>= 1) {
        const float v2 = __shfl_xor(cv, off);
        const int   i2 = __shfl_xor(ci, off);
        if (v2 > cv || (v2 == cv && i2 < ci)) { cv = v2; ci = i2; }
      }
      if (l == 0) {
        const unsigned long long pk = (1ULL << 63)
            | ((unsigned long long)__float_as_uint(cv) << 32)
            | (unsigned long long)(0xFFFFFFFFu - (unsigned)ci);
        __hip_atomic_store(&mycand[(size_t)t * NB_F + sub], pk,
                           __ATOMIC_RELEASE, __HIP_MEMORY_SCOPE_AGENT);
      }
      unsigned long long pk = 0ULL;
      if (l < NB_F) {
        pk = __hip_atomic_load(&mycand[(size_t)t * NB_F + l],
                               __ATOMIC_ACQUIRE, __HIP_MEMORY_SCOPE_AGENT);
        while (pk == 0ULL) {
          __builtin_amdgcn_s_sleep(1);
          pk = __hip_atomic_load(&mycand[(size_t)t * NB_F + l],
                                 __ATOMIC_ACQUIRE, __HIP_MEMORY_SCOPE_AGENT);
        }
      }
      #pragma unroll
      for (int off = 4; off; off >>= 1) {
        const unsigned long long o = __shfl_xor(pk, off, NB_F);
        pk = (o > pk) ? o : pk;
      }
      if (l == 0) {
        const int gi = (int)(0xFFFFFFFFu - (unsigned)(pk & 0xFFFFFFFFull));
        winLDS = gi;
        if (sub == 0) selg[t] = gi;
      }
    }
    __syncthreads();
    const int gbi = winLDS;
    lx = pos[3 * gbi]; ly = pos[3 * gbi + 1]; lz = pos[3 * gbi + 2];  // bcast, L1/L2-hit
  }
}

// ---------- distributed kmeans kernel: 8 blocks/branch x 512 threads (round-11) ----------
__global__ __launch_bounds__(TPB) void branch_kernel(const float* __restrict__ logits,
                                                     const float* __restrict__ logits1,
                                                     const float* __restrict__ pfirst,
                                                     const float* __restrict__ psec,
                                                     const int* __restrict__ sel_base,
                                                     float* __restrict__ feaT_base,
                                                     float* __restrict__ accum,
                                                     float* __restrict__ apay,
                                                     unsigned* __restrict__ aflag,
                                                     float* __restrict__ cpay,
                                                     unsigned* __restrict__ cflag) {
  const int br = blockIdx.x >> 3, sub = blockIdx.x & 7;
  const float* fea_all = ((br < 2) ? logits : logits1) + (size_t)(br & 1) * N_PTS * CD;
  const float* pos     = ((br < 2) ? pfirst : psec) + (size_t)(br & 1) * N_PTS * 3;
  const int* selg = sel_base + (size_t)br * NS;
  float* feaT = feaT_base + (size_t)br * NS * CD;
  float*    Apay  = apay  + (size_t)br * NB_K * APAY_N;
  unsigned* Aflag = aflag + br * NB_K;
  float*    Cpay  = cpay  + (size_t)br * NB_K * 16;
  unsigned* Cflag = cflag + br * NB_K;
  const int base = sub * LPTS;

  __shared__ Sm sm;
  extern __shared__ char dynraw[];
  const int tid = threadIdx.x, w = tid >> 6, l = tid & 63;

  for (int i = tid; i < NS; i += TPB) sm.sel[i] = selg[i];
  __syncthreads();

  // ================= gather sampled pos into LDS (full 2048, redundant) =========
  float* pos_s = (float*)dynraw;             // [NS*3] 0..24576
  float* stag  = (float*)(dynraw + 24576);   // [64][257] transpose staging
  float* wbuf  = (float*)(dynraw + 24576);   // 40960 B, reused after transpose
  float* mdbuf = (float*)(dynraw + 98304);   // [NS] (position) / [LPTS] (feature)
  for (int i = tid; i < NS; i += TPB) {
    const int s = sm.sel[i];
    pos_s[3 * i] = pos[3 * s]; pos_s[3 * i + 1] = pos[3 * s + 1]; pos_s[3 * i + 2] = pos[3 * s + 2];
  }

  // ================= gather + transpose OWN feature slice -> feaT ===============
  for (int tile = base; tile < base + LPTS; tile += 64) {
    __syncthreads();
    for (int rr = w; rr < 64; rr += 8) {
      const int srow = sm.sel[tile + rr];
      const float4 v = *(const float4*)&fea_all[(size_t)srow * CD + 4 * l];
      float* dst = &stag[rr * 257 + 4 * l];
      dst[0] = v.x; dst[1] = v.y; dst[2] = v.z; dst[3] = v.w;
    }
    __syncthreads();
    for (int dd = 0; dd < 32; dd++) {
      const int dim = w * 32 + dd;
      feaT[(size_t)dim * NS + tile + l] = stag[l * 257 + dim];
    }
  }
  __syncthreads();

  // ================= initial centroids (greedy, positions; redundant) ===========
  if (tid == 0) { sm.c3[0][0] = pos_s[0]; sm.c3[0][1] = pos_s[1]; sm.c3[0][2] = pos_s[2]; }
  __syncthreads();
  for (int k = 1; k < KC; k++) {
    float lv = -1.f; int li = 0x7fffffff;
    #pragma unroll
    for (int r = 0; r < 4; r++) {
      const int i = 4 * tid + r;
      const float x = pos_s[3 * i], y = pos_s[3 * i + 1], z = pos_s[3 * i + 2];
      float a = 0.f;
      for (int j = 0; j < k; j++) {
        const float dx = x - sm.c3[j][0], dy = y - sm.c3[j][1], dz = z - sm.c3[j][2];
        a += dx * dx + dy * dy + dz * dz;
      }
      if (a > lv) { lv = a; li = i; }
    }
    float bv; int bi;
    block_argmax(lv, li, sm, bv, bi);
    if (tid == 0) { sm.c3[k][0] = pos_s[3 * bi]; sm.c3[k][1] = pos_s[3 * bi + 1]; sm.c3[k][2] = pos_s[3 * bi + 2]; }
    __syncthreads();
  }

  // ================= one kmeans step on positions (full 2048, redundant) ========
  {
    float a3[KC][3]; float cn[KC];
    #pragma unroll
    for (int k = 0; k < KC; k++) { a3[k][0] = 0.f; a3[k][1] = 0.f; a3[k][2] = 0.f; cn[k] = 0.f; }
    #pragma unroll
    for (int r = 0; r < 4; r++) {
      const int i = 4 * tid + r;
      const float x = pos_s[3 * i], y = pos_s[3 * i + 1], z = pos_s[3 * i + 2];
      float best = FLT_MAX; int bk = 0;
      #pragma unroll
      for (int k = 0; k < KC; k++) {
        const float dx = x - sm.c3[k][0], dy = y - sm.c3[k][1], dz = z - sm.c3[k][2];
        const float s = dx * dx + dy * dy + dz * dz;
        if (s < best) { best = s; bk = k; }
      }
      sm.idx[i] = bk;
      #pragma unroll
      for (int k = 0; k < KC; k++) {
        const float m = (bk == k) ? 1.f : 0.f;
        a3[k][0] += m * x; a3[k][1] += m * y; a3[k][2] += m * z; cn[k] += m;
      }
    }
    reduce_counts(sm, cn);
    #pragma unroll
    for (int k = 0; k < KC; k++) {
      #pragma unroll
      for (int c = 0; c < 3; c++) {
        float s = a3[k][c];
        #pragma unroll
        for (int off = 32; off; off >>= 1) s += __shfl_xor(s, off);
        a3[k][c] = s;
      }
    }
    __syncthreads();
    if (l == 0) {
      #pragma unroll
      for (int k = 0; k < KC; k++) {
        wbuf[w * 16 + k * 3 + 0] = a3[k][0];
        wbuf[w * 16 + k * 3 + 1] = a3[k][1];
        wbuf[w * 16 + k * 3 + 2] = a3[k][2];
      }
    }
    __syncthreads();
    if (tid == 0) {
      for (int k = 0; k < KC; k++)
        for (int c = 0; c < 3; c++) {
          float s = 0.f;
          for (int g = 0; g < 8; g++) s += wbuf[g * 16 + k * 3 + c];
          sm.c3[k][c] = s / fmaxf(sm.cnt[k], 1.f);
        }
    }
    __syncthreads();
  }
  float psum = 0.f;
  #pragma unroll
  for (int r = 0; r < 4; r++) {
    const int i = 4 * tid + r; const int k = sm.idx[i];
    const float dx = pos_s[3 * i] - sm.c3[k][0];
    const float dy = pos_s[3 * i + 1] - sm.c3[k][1];
    const float dz = pos_s[3 * i + 2] - sm.c3[k][2];
    psum += dx * dx + dy * dy + dz * dz;
  }
  const float sse_n = sqrtf(block_sum(psum, sm));
  {  // empty-cluster fixup (positions, full 2048, redundant)
    int nmask = 0;
    #pragma unroll
    for (int k = 0; k < KC; k++) nmask |= (sm.cnt[k] == 0.f) ? (1 << k) : 0;
    if (nmask) {
      #pragma unroll
      for (int r = 0; r < 4; r++) {
        const int i = 4 * tid + r;
        const float x = pos_s[3 * i], y = pos_s[3 * i + 1], z = pos_s[3 * i + 2];
        float s = 0.f;
        for (int k = 0; k < KC; k++) {
          if (sm.cnt[k] > 0.f) {
            const float dx = x - sm.c3[k][0], dy = y - sm.c3[k][1], dz = z - sm.c3[k][2];
            s += sqrtf(dx * dx + dy * dy + dz * dz + 1e-12f);
          }
        }
        mdbuf[i] = s;
      }
      __syncthreads();
      top5(sm, mdbuf);
      if (tid == 0) {
        int cum = 0;
        for (int k = 0; k < KC; k++) {
          if (sm.cnt[k] == 0.f) {
            const int rk = (cum < KC) ? cum : (KC - 1);
            const int src = sm.far5[rk];
            sm.c3[k][0] = pos_s[3 * src]; sm.c3[k][1] = pos_s[3 * src + 1]; sm.c3[k][2] = pos_s[3 * src + 2];
            cum++;
          }
        }
      }
      __syncthreads();
    }
  }

  // ================= distributed kmeans on features =================
  assign3_local(sm, feaT, base);
  float sse_fin = iter_core(sm, wbuf, mdbuf, fea_all, feaT,
                            Apay, Aflag, Cpay, Cflag, base, sub, 1u);
  float sse_pre = sse_fin;
  bool done = fabsf(sse_fin) < TOLV;
  for (int it = 1; it < MAX_IT && !done; it++) {
    assign_full_local(sm, feaT, base);
    const float s2 = iter_core(sm, wbuf, mdbuf, fea_all, feaT,
                               Apay, Aflag, Cpay, Cflag, base, sub, (unsigned)(it + 1));
    sse_fin = s2;
    done = fabsf(s2 - sse_pre) < TOLV;
    sse_pre = s2;
  }
  if (sub == 0 && tid == 0) atomicAdd(&accum[1], sse_n + sse_fin);
}

// ---------- global point loss (cosine similarity) ----------
__global__ __launch_bounds__(256) void gp_kernel(const float* __restrict__ A,
                                                 const float* __restrict__ B,
                                                 float* __restrict__ accum) {
  __shared__ float bacc;
  const int tid = threadIdx.x, l = tid & 63, w = tid >> 6;
  if (tid == 0) bacc = 0.f;
  __syncthreads();
  const int gw = blockIdx.x * 4 + w;
  const int NW = gridDim.x * 4;
  float lsum = 0.f;
  for (int p = gw; p < 65536; p += NW) {
    const float4 a = *(const float4*)&A[(size_t)p * CD + 4 * l];
    const float4 b = *(const float4*)&B[(size_t)p * CD + 4 * l];
    float ab = a.x * b.x + a.y * b.y + a.z * b.z + a.w * b.w;
    float aa = a.x * a.x + a.y * a.y + a.z * a.z + a.w * a.w;
    float bb = b.x * b.x + b.y * b.y + b.z * b.z + b.w * b.w;
    #pragma unroll
    for (int off = 32; off; off >>= 1) {
      ab += __shfl_xor(ab, off); aa += __shfl_xor(aa, off); bb += __shfl_xor(bb, off);
    }
    if (l == 0) lsum += ab / fmaxf(sqrtf(aa) * sqrtf(bb), 1e-8f);
  }
  if (l == 0) atomicAdd(&bacc, lsum);
  __syncthreads();
  if (tid == 0) atomicAdd(&accum[0], bacc);
}

__global__ void fin_kernel(const float* __restrict__ accum, float* __restrict__ out) {
  out[0] = -accum[0] / 65536.0f + accum[1];
}

extern "C" void kernel_launch(void* const* d_in, const int* in_sizes, int n_in,
                              void* d_out, int out_size, void* d_ws, size_t ws_size,
                              hipStream_t stream) {
  const float* logits  = (const float*)d_in[0];
  const float* logits1 = (const float*)d_in[1];
  const float* pfirst  = (const float*)d_in[2];
  const float* psec    = (const float*)d_in[3];
  float* out = (float*)d_out;
  float* wsf = (float*)d_ws;
  // workspace layout (float offsets):
  float* accum = wsf;                                          // [0..16)
  int* selg = (int*)(wsf + 16);                                // 4*NS ints        @16
  unsigned long long* cand = (unsigned long long*)(wsf + 16 + 4 * NS);  // @8208 (byte%8==0)
  unsigned* aflag = (unsigned*)(wsf + 139280);                 // after cand (131072 floats)
  unsigned* cflag = (unsigned*)(wsf + 139312);
  float* apay = wsf + 139344;                                  // 4*8*1285 = 41120 floats
  float* cpay = wsf + 180464;                                  // 4*8*16 = 512 floats
  float* feaT = wsf + 180976;                                  // 4 branches x [CD][NS] = 8 MB

  static std::once_flag once;
  std::call_once(once, []() {
    (void)hipFuncSetAttribute((const void*)branch_kernel,
                              hipFuncAttributeMaxDynamicSharedMemorySize, DYN_K);
    (void)hipGetLastError();
  });

  // zero accum + selg + cand + flags (fresh cand slots + flag seqs start at 0 -> poll ==n
  // with n>=1 is ABA-free; payload regions need no zeroing, guarded by flags)
  (void)hipMemsetAsync(wsf, 0, (size_t)139344 * 4, stream);
  gp_kernel<<<1024, 256, 0, stream>>>(logits, logits1, accum);
  fps_kernel<<<4 * NB_F, TPB_F, 0, stream>>>(pfirst, psec, selg, cand);
  branch_kernel<<<4 * NB_K, TPB, DYN_K, stream>>>(logits, logits1, pfirst, psec,
                                                  selg, feaT, accum,
                                                  apay, aflag, cpay, cflag);
  fin_kernel<<<1, 1, 0, stream>>>(accum, out);
}